// Round 7
// baseline (691.052 us; speedup 1.0000x reference)
//
#include <hip/hip_runtime.h>
#include <math.h>

#define M_EDGES 50000
#define CHUNK 1024

// binned-scatter parameters
#define NBMAX 200      // max buckets per side (LDS arrays sized to this)
#define TILE_E 4096    // pairs per block, edge-bin pass
#define TILE_V 4096    // pairs per block, vtx-bin pass
#define CAPL_E 44      // LDS staging capacity per bucket (lambda ~20.9)
#define CAPL_V 32      // LDS staging capacity per bucket (lambda ~20.9)

typedef unsigned int u32;
typedef unsigned short u16;
typedef float f32x4 __attribute__((ext_vector_type(4)));
typedef short bf16x8 __attribute__((ext_vector_type(8)));

__device__ __forceinline__ float bflo(u32 u) { return __uint_as_float(u << 16); }
__device__ __forceinline__ float bfhi(u32 u) { return __uint_as_float(u & 0xffff0000u); }
__device__ __forceinline__ u32 packbf(float x, float y) {   // RNE both halves
  u32 a = __float_as_uint(x); a += 0x7fffu + ((a >> 16) & 1u);
  u32 b = __float_as_uint(y); b += 0x7fffu + ((b >> 16) & 1u);
  return (a >> 16) | (b & 0xffff0000u);
}
__device__ __forceinline__ u32 bf16rne(float x) {
  u32 a = __float_as_uint(x);
  a += 0x7fffu + ((a >> 16) & 1u);
  return a >> 16;
}
// split f into bf16 hi + bf16 lo with f ~= hi + lo (error ~2^-18 rel)
__device__ __forceinline__ void bfsplit(float f, u32& h, u32& l) {
  h = bf16rne(f);
  const float hf = __uint_as_float(h << 16);
  l = bf16rne(f - hf);
}

// ---------------- binned scatter, pass A (edge side) ----------------
// Entry: v (17b) | e_lo (<<17).
__global__ __launch_bounds__(256) void bin_edge_kernel(
    const int* __restrict__ pair_e, const int* __restrict__ pair_v,
    u32* __restrict__ out, int* __restrict__ gcur,
    int P, int SE, int NB) {
  __shared__ int lcnt[NBMAX];
  __shared__ int gbase[NBMAX];
  __shared__ u32 stage[NBMAX][CAPL_E];
  const int tid = (int)threadIdx.x;
  const int p0 = blockIdx.x * TILE_E;
  const int pend = (p0 + TILE_E < P) ? p0 + TILE_E : P;
  const u32 maskE = (1u << SE) - 1u;
  for (int b = tid; b < NB; b += 256) lcnt[b] = 0;
  __syncthreads();
  for (int p = p0 + tid; p < pend; p += 256) {
    const int e = pair_e[p];
    const int v = pair_v[p];
    const int b = e >> SE;
    const u32 entry = (u32)v | (((u32)e & maskE) << 17);
    const int pos = atomicAdd(&lcnt[b], 1);
    if (pos < CAPL_E) stage[b][pos] = entry;
    else out[atomicAdd(&gcur[b], 1)] = entry;   // rare overflow: direct append
  }
  __syncthreads();
  for (int b = tid; b < NB; b += 256) {
    const int n = lcnt[b] < CAPL_E ? lcnt[b] : CAPL_E;
    gbase[b] = atomicAdd(&gcur[b], n);
  }
  __syncthreads();
  const int wv = tid >> 6, lane = tid & 63;
  for (int b = wv; b < NB; b += 4) {
    const int n = lcnt[b] < CAPL_E ? lcnt[b] : CAPL_E;
    if (lane < n) out[gbase[b] + lane] = stage[b][lane];   // n <= 44 < 64
  }
}

// ---------------- binned scatter, pass A (vertex side) ----------------
// Entry: {v_lo | e<<SV, src}.
__global__ __launch_bounds__(256) void bin_vtx_kernel(
    const int* __restrict__ pair_e, const int* __restrict__ pair_v,
    const int* __restrict__ src_v,
    uint2* __restrict__ out, int* __restrict__ gcur,
    int P, int SV, int NB) {
  __shared__ int lcnt[NBMAX];
  __shared__ int gbase[NBMAX];
  __shared__ uint2 stage[NBMAX][CAPL_V];
  const int tid = (int)threadIdx.x;
  const int p0 = blockIdx.x * TILE_V;
  const int pend = (p0 + TILE_V < P) ? p0 + TILE_V : P;
  const u32 maskV = (1u << SV) - 1u;
  for (int b = tid; b < NB; b += 256) lcnt[b] = 0;
  __syncthreads();
  for (int p = p0 + tid; p < pend; p += 256) {
    const int e = pair_e[p];
    const int v = pair_v[p];
    const int s = src_v[p];
    const int b = v >> SV;
    uint2 entry;
    entry.x = ((u32)v & maskV) | ((u32)e << SV);
    entry.y = (u32)s;
    const int pos = atomicAdd(&lcnt[b], 1);
    if (pos < CAPL_V) stage[b][pos] = entry;
    else out[atomicAdd(&gcur[b], 1)] = entry;
  }
  __syncthreads();
  for (int b = tid; b < NB; b += 256) {
    const int n = lcnt[b] < CAPL_V ? lcnt[b] : CAPL_V;
    gbase[b] = atomicAdd(&gcur[b], n);
  }
  __syncthreads();
  const int wv = tid >> 6, lane = tid & 63;
  for (int b = wv; b < NB; b += 4) {
    const int n = lcnt[b] < CAPL_V ? lcnt[b] : CAPL_V;
    if (lane < n) out[gbase[b] + lane] = stage[b][lane];   // n <= 32 < 64
  }
}

__global__ void init_gcur_kernel(int* __restrict__ ge, int* __restrict__ gv,
                                 int NBE, int NBV, int capgE, int capgV) {
  const int t = (int)threadIdx.x;
  if (t < NBE) ge[t] = t * capgE;
  if (t < NBV) gv[t] = t * capgV;
}

// ---------------- bucket-local degree histogram ----------------
__global__ __launch_bounds__(256) void bucket_hist_kernel(
    const u32* __restrict__ entE, const int* __restrict__ gcurE, int* __restrict__ cnt_e,
    const uint2* __restrict__ entV, const int* __restrict__ gcurV, int* __restrict__ cnt_v,
    int NBE, int SE, int capgE, int SV, int capgV, int M, int N) {
  __shared__ int h[1024];
  const int b = (int)blockIdx.x;
  const int tid = (int)threadIdx.x;
  if (b < NBE) {
    const int nb = 1 << SE;
    for (int t = tid; t < nb; t += 256) h[t] = 0;
    __syncthreads();
    const int end = gcurE[b];
    for (int i = b * capgE + tid; i < end; i += 256)
      atomicAdd(&h[entE[i] >> 17], 1);
    __syncthreads();
    const int base = b << SE;
    for (int t = tid; t < nb; t += 256)
      if (base + t < M) cnt_e[base + t] = h[t];
  } else {
    const int bb = b - NBE;
    const int nb = 1 << SV;
    for (int t = tid; t < nb; t += 256) h[t] = 0;
    __syncthreads();
    const int end = gcurV[bb];
    const u32 mask = (1u << SV) - 1u;
    for (int i = bb * capgV + tid; i < end; i += 256)
      atomicAdd(&h[entV[i].x & mask], 1);
    __syncthreads();
    const int base = bb << SV;
    for (int t = tid; t < nb; t += 256)
      if (base + t < N) cnt_v[base + t] = h[t];
  }
}

// ---------------- pass B: unbin into final CSR (edge side) ----------------
__global__ __launch_bounds__(512) void unbin_edge_kernel(
    const u32* __restrict__ ent, const int* __restrict__ gcur,
    int* __restrict__ cur_e, int* __restrict__ edge_vtx,
    int SE, int capg) {
  const int b = blockIdx.x;
  const int end = gcur[b];
  const int ebase = b << SE;
  for (int i = b * capg + (int)threadIdx.x; i < end; i += 512) {
    const u32 w = ent[i];
    const int v = (int)(w & 0x1ffffu);
    const int e = ebase + (int)(w >> 17);
    edge_vtx[atomicAdd(&cur_e[e], 1)] = v;
  }
}

// ---------------- pass B: unbin into final CSR (vertex side) ----------------
// Writes BOTH vtx_es (for attn pass) and compact vtx_edge (for P2/P6).
__global__ __launch_bounds__(512) void unbin_vtx_kernel(
    const uint2* __restrict__ ent, const int* __restrict__ gcur,
    int* __restrict__ cur_v, int2* __restrict__ vtx_es, int* __restrict__ vtx_edge,
    const float* __restrict__ svec, const float* __restrict__ dvec,
    int SV, int capg) {
  const int b = blockIdx.x;
  const int end = gcur[b];
  const int vbase = b << SV;
  const u32 maskV = (1u << SV) - 1u;
  for (int i = b * capg + (int)threadIdx.x; i < end; i += 512) {
    const uint2 w = ent[i];
    const int v = vbase + (int)(w.x & maskV);
    const int e = (int)(w.x >> SV);
    float sc = svec[w.y] + dvec[v];
    sc = sc > 0.f ? sc : 0.2f * sc;           // leaky_relu(0.2)
    sc = fminf(fmaxf(sc, 0.001f), 5.0f);      // clip
    const int iv = atomicAdd(&cur_v[v], 1);
    vtx_es[iv] = make_int2(e, __float_as_int(__expf(sc)));
    vtx_edge[iv] = e;
  }
}

// ---------------- hierarchical scan, phase A ----------------
__global__ __launch_bounds__(1024) void blocksum_kernel(
    const int* __restrict__ cnt_e, const int* __restrict__ cnt_v,
    int* __restrict__ part, int CE, int M, int N) {
  const int b = blockIdx.x;
  const int* cnt;
  int n, chunk;
  if (b < CE) { cnt = cnt_e; n = M; chunk = b; }
  else        { cnt = cnt_v; n = N; chunk = b - CE; }
  const int i = chunk * CHUNK + (int)threadIdx.x;
  int x = (i < n) ? cnt[i] : 0;
#pragma unroll
  for (int m = 32; m >= 1; m >>= 1) x += __shfl_xor(x, m, 64);
  __shared__ int ws[16];
  if ((threadIdx.x & 63) == 0) ws[threadIdx.x >> 6] = x;
  __syncthreads();
  if (threadIdx.x == 0) {
    int t = 0;
#pragma unroll
    for (int q = 0; q < 16; ++q) t += ws[q];
    part[b] = t;
  }
}

// ---------------- phase B ----------------
__global__ __launch_bounds__(256) void partscan_kernel(
    int* __restrict__ part, int CE, int CV,
    int* __restrict__ off_e, int* __restrict__ off_v, int M, int N) {
  __shared__ int sh[256];
  const int tid = (int)threadIdx.x;
  for (int s = 0; s < 2; ++s) {
    const int base = s ? CE : 0;
    const int count = s ? CV : CE;   // both <= 256
    int x = (tid < count) ? part[base + tid] : 0;
    sh[tid] = x;
    __syncthreads();
    for (int ofs = 1; ofs < 256; ofs <<= 1) {
      int v = (tid >= ofs) ? sh[tid - ofs] : 0;
      __syncthreads();
      sh[tid] += v;
      __syncthreads();
    }
    if (tid < count) part[base + tid] = sh[tid] - x;   // exclusive
    if (tid == 0) {
      const int tot = sh[count - 1];
      if (s == 0) off_e[M] = tot; else off_v[N] = tot;
    }
    __syncthreads();
  }
}

// ---------------- phase C ----------------
__global__ __launch_bounds__(1024) void blockscan_kernel(
    const int* __restrict__ cnt_e, const int* __restrict__ cnt_v,
    const int* __restrict__ part,
    int* __restrict__ off_e, int* __restrict__ off_v,
    int* __restrict__ cur_e, int* __restrict__ cur_v,
    float* __restrict__ de_inv, float* __restrict__ dv_inv, float* __restrict__ dv_isqrt,
    int CE, int M, int N) {
  __shared__ int sh[CHUNK];
  const int b = blockIdx.x;
  const int tid = (int)threadIdx.x;
  const int* cnt;
  int n, chunk;
  int *off, *cur;
  float *i1, *i2;
  if (b < CE) { cnt = cnt_e; n = M; chunk = b;      off = off_e; cur = cur_e; i1 = de_inv; i2 = nullptr; }
  else        { cnt = cnt_v; n = N; chunk = b - CE; off = off_v; cur = cur_v; i1 = dv_inv; i2 = dv_isqrt; }
  const int i = chunk * CHUNK + tid;
  const int x = (i < n) ? cnt[i] : 0;
  sh[tid] = x;
  __syncthreads();
  for (int ofs = 1; ofs < CHUNK; ofs <<= 1) {
    int v = (tid >= ofs) ? sh[tid - ofs] : 0;
    __syncthreads();
    sh[tid] += v;
    __syncthreads();
  }
  if (i < n) {
    const int o = part[b] + sh[tid] - x;
    off[i] = o;
    cur[i] = o;              // cursor pre-initialized to offset
    const float m = (float)(x > 1 ? x : 1);
    i1[i] = 1.0f / m;
    if (i2) i2[i] = 1.0f / sqrtf(m);
  }
}

// ---------------- W split ----------------
__global__ __launch_bounds__(256) void prep_w_kernel(
    const float* __restrict__ W, u16* __restrict__ whi, u16* __restrict__ wlo) {
  const int i = (int)blockIdx.x * 256 + (int)threadIdx.x;
  if (i >= 128 * 128) return;
  u32 h, l;
  bfsplit(W[i], h, l);
  whi[i] = (u16)h;
  wlo[i] = (u16)l;
}

// ---------------- MFMA GEMM (split-bf16, 3 terms) ----------------
#define XPAD 136
__global__ __launch_bounds__(256) void gemm_mfma_kernel(
    const float* __restrict__ X,
    const u16* __restrict__ whi, const u16* __restrict__ wlo,
    const float* __restrict__ bias, const float* __restrict__ wsrc,
    const float* __restrict__ wdst, const float* __restrict__ dv_isqrt,
    u16* __restrict__ Hb, float* __restrict__ s_out, float* __restrict__ d_out,
    int N) {
  __shared__ u16 xhi[64 * XPAD];
  __shared__ u16 xlo[64 * XPAD];
  __shared__ float sred[64];
  __shared__ float dred[64];
  const int tid = (int)threadIdx.x;
  const int row0 = (int)blockIdx.x * 64;

  if (tid < 64) { sred[tid] = 0.f; dred[tid] = 0.f; }
  for (int g = tid; g < 64 * 32; g += 256) {
    const int r = g >> 5;
    const int k4 = (g & 31) << 2;
    int rr = row0 + r; if (rr >= N) rr = N - 1;
    const float4 v = *(const float4*)(X + (size_t)rr * 128 + k4);
    u32 h0, l0, h1, l1, h2, l2, h3, l3;
    bfsplit(v.x, h0, l0); bfsplit(v.y, h1, l1);
    bfsplit(v.z, h2, l2); bfsplit(v.w, h3, l3);
    *(uint2*)(xhi + r * XPAD + k4) = make_uint2(h0 | (h1 << 16), h2 | (h3 << 16));
    *(uint2*)(xlo + r * XPAD + k4) = make_uint2(l0 | (l1 << 16), l2 | (l3 << 16));
  }
  __syncthreads();

  const int wv = tid >> 6;       // wave id: col slice
  const int l  = tid & 63;
  const int lr = l & 15;         // A-row / B-col within 16
  const int lg = l >> 4;         // k-group
  const int cb = wv * 32;

  f32x4 zero = {0.f, 0.f, 0.f, 0.f};
  f32x4 acc[4][2];
#pragma unroll
  for (int rt = 0; rt < 4; ++rt) { acc[rt][0] = zero; acc[rt][1] = zero; }

#pragma unroll
  for (int kk = 0; kk < 4; ++kk) {
    const int kof = kk * 32 + lg * 8;
    const bf16x8 bh0 = *(const bf16x8*)(whi + (size_t)(cb + lr) * 128 + kof);
    const bf16x8 bh1 = *(const bf16x8*)(whi + (size_t)(cb + 16 + lr) * 128 + kof);
    const bf16x8 bl0 = *(const bf16x8*)(wlo + (size_t)(cb + lr) * 128 + kof);
    const bf16x8 bl1 = *(const bf16x8*)(wlo + (size_t)(cb + 16 + lr) * 128 + kof);
#pragma unroll
    for (int rt = 0; rt < 4; ++rt) {
      const bf16x8 ah = *(const bf16x8*)(xhi + (rt * 16 + lr) * XPAD + kof);
      const bf16x8 al = *(const bf16x8*)(xlo + (rt * 16 + lr) * XPAD + kof);
      acc[rt][0] = __builtin_amdgcn_mfma_f32_16x16x32_bf16(ah, bh0, acc[rt][0], 0, 0, 0);
      acc[rt][1] = __builtin_amdgcn_mfma_f32_16x16x32_bf16(ah, bh1, acc[rt][1], 0, 0, 0);
      acc[rt][0] = __builtin_amdgcn_mfma_f32_16x16x32_bf16(al, bh0, acc[rt][0], 0, 0, 0);
      acc[rt][1] = __builtin_amdgcn_mfma_f32_16x16x32_bf16(al, bh1, acc[rt][1], 0, 0, 0);
      acc[rt][0] = __builtin_amdgcn_mfma_f32_16x16x32_bf16(ah, bl0, acc[rt][0], 0, 0, 0);
      acc[rt][1] = __builtin_amdgcn_mfma_f32_16x16x32_bf16(ah, bl1, acc[rt][1], 0, 0, 0);
    }
  }

  const int c0 = cb + lr, c1 = cb + 16 + lr;
  const float bb0 = bias[c0], bb1 = bias[c1];
  const float ws0 = wsrc[c0], ws1 = wsrc[c1];
  const float wd0 = wdst[c0], wd1 = wdst[c1];
#pragma unroll
  for (int rt = 0; rt < 4; ++rt) {
#pragma unroll
    for (int j = 0; j < 4; ++j) {
      const int rl = rt * 16 + lg * 4 + j;
      const int row = row0 + rl;
      const float h0 = acc[rt][0][j] + bb0;
      const float h1 = acc[rt][1][j] + bb1;
      float sp = h0 * ws0 + h1 * ws1;
      float dp = h0 * wd0 + h1 * wd1;
#pragma unroll
      for (int m = 1; m <= 8; m <<= 1) {
        sp += __shfl_xor(sp, m, 64);
        dp += __shfl_xor(dp, m, 64);
      }
      if (lr == 0) { atomicAdd(&sred[rl], sp); atomicAdd(&dred[rl], dp); }
      if (row < N) {
        const float sc = dv_isqrt[row];
        Hb[(size_t)row * 128 + c0] = (u16)bf16rne(h0 * sc);
        Hb[(size_t)row * 128 + c1] = (u16)bf16rne(h1 * sc);
      }
    }
  }
  __syncthreads();
  if (tid < 64) {
    const int row = row0 + tid;
    if (row < N) { s_out[row] = sred[tid]; d_out[row] = dred[tid]; }
  }
}

#define ACC4(r, p)                                         \
  a[0] += bflo((r).x) * (p); a[1] += bfhi((r).x) * (p);    \
  a[2] += bflo((r).y) * (p); a[3] += bfhi((r).y) * (p);

// ---------------- clamped-gather segment sum, channel-half split ----------------
// Grid = 2*gh blocks: blocks [0,gh) do channels [0,64), blocks [gh,2gh) do
// [64,128). A half-pass touches only half of each 256B source row -> per-XCD
// L2 footprint halves (12.8->6.4MB for bufM) -> gather-dup miss rate drops.
// Block issue order gives approximate temporal separation of the halves.
// Quarter q owns entries {t0+q,+4,+8,+12}; OOR slots clamp to last, weight 0
// (full 4-deep MLP in tails). lane cl covers 4 channels (uint2 = 8B load;
// 16 lanes x 8B = 128B coalesced per row-half).
__global__ __launch_bounds__(256) void seg_pass_kernel(
    const u16* __restrict__ src, u16* __restrict__ dst,
    const int* __restrict__ off, const int* __restrict__ lst,
    const float* __restrict__ post_scale, int nseg, int gh) {
  const int bid = (int)blockIdx.x;
  const int half = bid >= gh;
  const int co = half << 6;
  const int seg = (bid - (half ? gh : 0)) * 4 + ((int)threadIdx.x >> 6);
  if (seg >= nseg) return;
  const int lane = (int)threadIdx.x & 63;
  const int q = lane >> 4;
  const int cc = co + (lane & 15) * 4;   // channel base for this lane
  const int beg = off[seg], end = off[seg + 1];
  const int last = end - 1;
  float a[4] = {};
  for (int t0 = beg + q; t0 < end; t0 += 16) {
    const int t1 = t0 + 4, t2 = t0 + 8, t3 = t0 + 12;
    const int j0 = lst[t0];
    const int j1 = lst[t1 <= last ? t1 : last];
    const int j2 = lst[t2 <= last ? t2 : last];
    const int j3 = lst[t3 <= last ? t3 : last];
    const float w1 = t1 <= last ? 1.f : 0.f;
    const float w2 = t2 <= last ? 1.f : 0.f;
    const float w3 = t3 <= last ? 1.f : 0.f;
    const uint2 r0 = *(const uint2*)(src + (size_t)j0 * 128 + cc);
    const uint2 r1 = *(const uint2*)(src + (size_t)j1 * 128 + cc);
    const uint2 r2 = *(const uint2*)(src + (size_t)j2 * 128 + cc);
    const uint2 r3 = *(const uint2*)(src + (size_t)j3 * 128 + cc);
    ACC4(r0, 1.0f) ACC4(r1, w1) ACC4(r2, w2) ACC4(r3, w3)
  }
#pragma unroll
  for (int k = 0; k < 4; ++k) {
    a[k] += __shfl_xor(a[k], 16, 64);
    a[k] += __shfl_xor(a[k], 32, 64);
  }
  if (q != 0) return;
  const float ps = post_scale[seg];
  uint2 pk;
  pk.x = packbf(a[0] * ps, a[1] * ps);
  pk.y = packbf(a[2] * ps, a[3] * ps);
  *(uint2*)(dst + (size_t)seg * 128 + cc) = pk;
}

// ---------------- N-direction variant (P2/P6), channel-half split ----------------
__global__ __launch_bounds__(256) void segn_pass_kernel(
    const u16* __restrict__ src, void* __restrict__ dst,
    const int* __restrict__ off, const int* __restrict__ lst,
    const float* __restrict__ post_scale, int nseg, int gh, int final_mode) {
  const int bid = (int)blockIdx.x;
  const int half = bid >= gh;
  const int co = half << 6;
  const int seg = (bid - (half ? gh : 0)) * 4 + ((int)threadIdx.x >> 6);
  if (seg >= nseg) return;
  const int lane = (int)threadIdx.x & 63;
  const int q = lane >> 4;
  const int cc = co + (lane & 15) * 4;
  const int beg = off[seg], end = off[seg + 1];
  const int last = end - 1;
  float a[4] = {};
  for (int t0 = beg + q; t0 < end; t0 += 16) {
    const int t1 = t0 + 4, t2 = t0 + 8, t3 = t0 + 12;
    const int j0 = lst[t0];
    const int j1 = lst[t1 <= last ? t1 : last];
    const int j2 = lst[t2 <= last ? t2 : last];
    const int j3 = lst[t3 <= last ? t3 : last];
    const float w1 = t1 <= last ? 1.f : 0.f;
    const float w2 = t2 <= last ? 1.f : 0.f;
    const float w3 = t3 <= last ? 1.f : 0.f;
    const uint2 r0 = *(const uint2*)(src + (size_t)j0 * 128 + cc);
    const uint2 r1 = *(const uint2*)(src + (size_t)j1 * 128 + cc);
    const uint2 r2 = *(const uint2*)(src + (size_t)j2 * 128 + cc);
    const uint2 r3 = *(const uint2*)(src + (size_t)j3 * 128 + cc);
    ACC4(r0, 1.0f) ACC4(r1, w1) ACC4(r2, w2) ACC4(r3, w3)
  }
#pragma unroll
  for (int k = 0; k < 4; ++k) {
    a[k] += __shfl_xor(a[k], 16, 64);
    a[k] += __shfl_xor(a[k], 32, 64);
  }
  if (q != 0) return;
  const float ps = post_scale[seg];
#pragma unroll
  for (int k = 0; k < 4; ++k) a[k] *= ps;
  if (final_mode) {
#pragma unroll
    for (int k = 0; k < 4; ++k) a[k] = a[k] > 0.f ? a[k] : __expf(a[k]) - 1.0f;
    float* o = (float*)dst + (size_t)seg * 128 + cc;
    f32x4 v0 = {a[0], a[1], a[2], a[3]};
    __builtin_nontemporal_store(v0, (f32x4*)o);
  } else {
    uint2 pk;
    pk.x = packbf(a[0], a[1]);
    pk.y = packbf(a[2], a[3]);
    *(uint2*)((u16*)dst + (size_t)seg * 128 + cc) = pk;
  }
}

// ---------------- attention e2v (P4), channel-half split ----------------
__global__ __launch_bounds__(256) void attn_pass_kernel(
    const u16* __restrict__ src, u16* __restrict__ dst,
    const int* __restrict__ off, const int2* __restrict__ lst_es, int nseg, int gh) {
  const int bid = (int)blockIdx.x;
  const int half = bid >= gh;
  const int co = half << 6;
  const int seg = (bid - (half ? gh : 0)) * 4 + ((int)threadIdx.x >> 6);
  if (seg >= nseg) return;
  const int lane = (int)threadIdx.x & 63;
  const int q = lane >> 4;
  const int cc = co + (lane & 15) * 4;
  const int beg = off[seg], end = off[seg + 1];
  const int last = end - 1;
  float a[4] = {};
  float den = 0.f;
  for (int t0 = beg + q; t0 < end; t0 += 16) {
    const int t1 = t0 + 4, t2 = t0 + 8, t3 = t0 + 12;
    const int2 e0 = lst_es[t0];
    const int2 e1 = lst_es[t1 <= last ? t1 : last];
    const int2 e2 = lst_es[t2 <= last ? t2 : last];
    const int2 e3 = lst_es[t3 <= last ? t3 : last];
    const float s0 = __int_as_float(e0.y);
    const float s1 = t1 <= last ? __int_as_float(e1.y) : 0.f;
    const float s2 = t2 <= last ? __int_as_float(e2.y) : 0.f;
    const float s3 = t3 <= last ? __int_as_float(e3.y) : 0.f;
    const uint2 r0 = *(const uint2*)(src + (size_t)e0.x * 128 + cc);
    const uint2 r1 = *(const uint2*)(src + (size_t)e1.x * 128 + cc);
    const uint2 r2 = *(const uint2*)(src + (size_t)e2.x * 128 + cc);
    const uint2 r3 = *(const uint2*)(src + (size_t)e3.x * 128 + cc);
    ACC4(r0, s0) ACC4(r1, s1) ACC4(r2, s2) ACC4(r3, s3)
    den += s0 + s1 + s2 + s3;
  }
#pragma unroll
  for (int k = 0; k < 4; ++k) {
    a[k] += __shfl_xor(a[k], 16, 64);
    a[k] += __shfl_xor(a[k], 32, 64);
  }
  den += __shfl_xor(den, 16, 64);
  den += __shfl_xor(den, 32, 64);
  const float inv = (end > beg) ? 1.0f / den : 0.0f;
  if (q != 0) return;
  uint2 pk;
  pk.x = packbf(a[0] * inv, a[1] * inv);
  pk.y = packbf(a[2] * inv, a[3] * inv);
  *(uint2*)(dst + (size_t)seg * 128 + cc) = pk;
}

extern "C" void kernel_launch(void* const* d_in, const int* in_sizes, int n_in,
                              void* d_out, int out_size, void* d_ws, size_t ws_size,
                              hipStream_t stream) {
  const float* X      = (const float*)d_in[0];
  const int*   pair_v = (const int*)d_in[1];
  const int*   pair_e = (const int*)d_in[2];
  const int*   src_v  = (const int*)d_in[3];
  const float* W      = (const float*)d_in[4];
  const float* bias   = (const float*)d_in[5];
  const float* wsrc   = (const float*)d_in[6];
  const float* wdst   = (const float*)d_in[7];

  const int N = in_sizes[0] / 128;
  const int P = in_sizes[1];
  const int M = M_EDGES;   // fixed by problem definition (pair_e in [0, 50000))
  const int CE = (M + CHUNK - 1) / CHUNK;   // <=256 for partscan
  const int CV = (N + CHUNK - 1) / CHUNK;   // <=256 for partscan

  int SE = 8;
  while ((((M - 1) >> SE) + 1) > NBMAX) ++SE;
  const int NBE = ((M - 1) >> SE) + 1;
  int SV = 9;
  while ((((N - 1) >> SV) + 1) > NBMAX) ++SV;
  const int NBV = ((N - 1) >> SV) + 1;
  const int capgE = P / NBE + P / (NBE * 8) + 256;
  const int capgV = P / NBV + P / (NBV * 8) + 256;

  char* w = (char*)d_ws;
  auto alloc = [&](size_t bytes) -> char* {
    char* p = w;
    w += (bytes + 255) & ~(size_t)255;
    return p;
  };
  int*   cnt_e     = (int*)alloc((size_t)M * 4);
  int*   cnt_v     = (int*)alloc((size_t)N * 4);
  int*   cur_e     = (int*)alloc((size_t)M * 4);
  int*   cur_v     = (int*)alloc((size_t)N * 4);
  int*   part      = (int*)alloc((size_t)(CE + CV) * 4);
  int*   edge_off  = (int*)alloc((size_t)(M + 1) * 4);
  int*   vtx_off   = (int*)alloc((size_t)(N + 1) * 4);
  float* de_inv    = (float*)alloc((size_t)M * 4);
  float* dv_inv    = (float*)alloc((size_t)N * 4);
  float* dv_isqrt  = (float*)alloc((size_t)N * 4);
  float* svec      = (float*)alloc((size_t)N * 4);
  float* dvec      = (float*)alloc((size_t)N * 4);
  int*   edge_vtx  = (int*)alloc((size_t)P * 4);
  int2*  vtx_es    = (int2*)alloc((size_t)P * 8);
  int*   vtx_edge  = (int*)alloc((size_t)P * 4);
  u16*   bufN      = (u16*)alloc((size_t)N * 128 * 2);  // Hs -> Hs2 -> Xv1 (bf16)
  u16*   bufM      = (u16*)alloc((size_t)M * 128 * 2);  // Xe -> Xe1 -> Xe2 (bf16)
  u32*   binE      = (u32*)alloc((size_t)NBE * capgE * 4);
  uint2* binV      = (uint2*)alloc((size_t)NBV * capgV * 8);
  int*   gcur_e    = (int*)alloc((size_t)NBE * 4);
  int*   gcur_v    = (int*)alloc((size_t)NBV * 4);
  u16*   whi_g     = (u16*)alloc((size_t)128 * 128 * 2);
  u16*   wlo_g     = (u16*)alloc((size_t)128 * 128 * 2);

  prep_w_kernel<<<64, 256, 0, stream>>>(W, whi_g, wlo_g);
  init_gcur_kernel<<<1, 256, 0, stream>>>(gcur_e, gcur_v, NBE, NBV, capgE, capgV);
  bin_edge_kernel<<<(P + TILE_E - 1) / TILE_E, 256, 0, stream>>>(
      pair_e, pair_v, binE, gcur_e, P, SE, NBE);
  bin_vtx_kernel<<<(P + TILE_V - 1) / TILE_V, 256, 0, stream>>>(
      pair_e, pair_v, src_v, binV, gcur_v, P, SV, NBV);
  bucket_hist_kernel<<<NBE + NBV, 256, 0, stream>>>(
      binE, gcur_e, cnt_e, binV, gcur_v, cnt_v, NBE, SE, capgE, SV, capgV, M, N);
  blocksum_kernel<<<CE + CV, 1024, 0, stream>>>(cnt_e, cnt_v, part, CE, M, N);
  partscan_kernel<<<1, 256, 0, stream>>>(part, CE, CV, edge_off, vtx_off, M, N);
  blockscan_kernel<<<CE + CV, 1024, 0, stream>>>(cnt_e, cnt_v, part, edge_off, vtx_off,
                                                 cur_e, cur_v, de_inv, dv_inv, dv_isqrt,
                                                 CE, M, N);
  gemm_mfma_kernel<<<(N + 63) / 64, 256, 0, stream>>>(X, whi_g, wlo_g, bias, wsrc, wdst,
                                                      dv_isqrt, bufN, svec, dvec, N);
  unbin_edge_kernel<<<NBE, 512, 0, stream>>>(binE, gcur_e, cur_e, edge_vtx, SE, capgE);
  unbin_vtx_kernel<<<NBV, 512, 0, stream>>>(binV, gcur_v, cur_v, vtx_es, vtx_edge,
                                            svec, dvec, SV, capgV);

  const int gm = (M + 3) / 4;
  const int gn = (N + 3) / 4;
  // P1: Xe  = de_inv * sum Hs[v]          (dv_isqrt folded into Hs at GEMM)
  seg_pass_kernel<<<2 * gm, 256, 0, stream>>>(bufN, bufM, edge_off, edge_vtx, de_inv, M, gm);
  // P2: Hs2 = dv_isqrt * sum Xe[e]
  segn_pass_kernel<<<2 * gn, 256, 0, stream>>>(bufM, bufN, vtx_off, vtx_edge, dv_isqrt, N, gn, 0);
  // P3: Xe1 = de_inv * sum Hs2[v]
  seg_pass_kernel<<<2 * gm, 256, 0, stream>>>(bufN, bufM, edge_off, edge_vtx, de_inv, M, gm);
  // P4: Xv1 = softmax-weighted sum of Xe1[e]
  attn_pass_kernel<<<2 * gn, 256, 0, stream>>>(bufM, bufN, vtx_off, vtx_es, N, gn);
  // P5: Xe2 = de_inv * sum Xv1[v]
  seg_pass_kernel<<<2 * gm, 256, 0, stream>>>(bufN, bufM, edge_off, edge_vtx, de_inv, M, gm);
  // P6: out = elu(dv_inv * sum Xe2[e])  -> fp32 nontemporal
  segn_pass_kernel<<<2 * gn, 256, 0, stream>>>(bufM, d_out, vtx_off, vtx_edge, dv_inv, N, gn, 1);
}

// Round 8
// 617.197 us; speedup vs baseline: 1.1197x; 1.1197x over previous
//
#include <hip/hip_runtime.h>
#include <math.h>

#define M_EDGES 50000
#define CHUNK 1024

// binned-scatter parameters
#define NBMAX 200      // max buckets per side (LDS arrays sized to this)
#define TILE_E 4096    // pairs per block, edge-bin pass
#define TILE_V 4096    // pairs per block, vtx-bin pass
#define CAPL_E 44      // LDS staging capacity per bucket (lambda ~20.9)
#define CAPL_V 32      // LDS staging capacity per bucket (lambda ~20.9)

typedef unsigned int u32;
typedef unsigned short u16;
typedef float f32x4 __attribute__((ext_vector_type(4)));
typedef short bf16x8 __attribute__((ext_vector_type(8)));

__device__ __forceinline__ float bflo(u32 u) { return __uint_as_float(u << 16); }
__device__ __forceinline__ float bfhi(u32 u) { return __uint_as_float(u & 0xffff0000u); }
__device__ __forceinline__ u32 packbf(float x, float y) {   // RNE both halves
  u32 a = __float_as_uint(x); a += 0x7fffu + ((a >> 16) & 1u);
  u32 b = __float_as_uint(y); b += 0x7fffu + ((b >> 16) & 1u);
  return (a >> 16) | (b & 0xffff0000u);
}
__device__ __forceinline__ u32 bf16rne(float x) {
  u32 a = __float_as_uint(x);
  a += 0x7fffu + ((a >> 16) & 1u);
  return a >> 16;
}
// split f into bf16 hi + bf16 lo with f ~= hi + lo (error ~2^-18 rel)
__device__ __forceinline__ void bfsplit(float f, u32& h, u32& l) {
  h = bf16rne(f);
  const float hf = __uint_as_float(h << 16);
  l = bf16rne(f - hf);
}

// ---------------- binned scatter, pass A (edge side) ----------------
// Entry: v (17b) | e_lo (<<17).
__global__ __launch_bounds__(256) void bin_edge_kernel(
    const int* __restrict__ pair_e, const int* __restrict__ pair_v,
    u32* __restrict__ out, int* __restrict__ gcur,
    int P, int SE, int NB) {
  __shared__ int lcnt[NBMAX];
  __shared__ int gbase[NBMAX];
  __shared__ u32 stage[NBMAX][CAPL_E];
  const int tid = (int)threadIdx.x;
  const int p0 = blockIdx.x * TILE_E;
  const int pend = (p0 + TILE_E < P) ? p0 + TILE_E : P;
  const u32 maskE = (1u << SE) - 1u;
  for (int b = tid; b < NB; b += 256) lcnt[b] = 0;
  __syncthreads();
  for (int p = p0 + tid; p < pend; p += 256) {
    const int e = pair_e[p];
    const int v = pair_v[p];
    const int b = e >> SE;
    const u32 entry = (u32)v | (((u32)e & maskE) << 17);
    const int pos = atomicAdd(&lcnt[b], 1);
    if (pos < CAPL_E) stage[b][pos] = entry;
    else out[atomicAdd(&gcur[b], 1)] = entry;   // rare overflow: direct append
  }
  __syncthreads();
  for (int b = tid; b < NB; b += 256) {
    const int n = lcnt[b] < CAPL_E ? lcnt[b] : CAPL_E;
    gbase[b] = atomicAdd(&gcur[b], n);
  }
  __syncthreads();
  const int wv = tid >> 6, lane = tid & 63;
  for (int b = wv; b < NB; b += 4) {
    const int n = lcnt[b] < CAPL_E ? lcnt[b] : CAPL_E;
    if (lane < n) out[gbase[b] + lane] = stage[b][lane];   // n <= 44 < 64
  }
}

// ---------------- binned scatter, pass A (vertex side) ----------------
// Entry: {v_lo | e<<SV, src}.
__global__ __launch_bounds__(256) void bin_vtx_kernel(
    const int* __restrict__ pair_e, const int* __restrict__ pair_v,
    const int* __restrict__ src_v,
    uint2* __restrict__ out, int* __restrict__ gcur,
    int P, int SV, int NB) {
  __shared__ int lcnt[NBMAX];
  __shared__ int gbase[NBMAX];
  __shared__ uint2 stage[NBMAX][CAPL_V];
  const int tid = (int)threadIdx.x;
  const int p0 = blockIdx.x * TILE_V;
  const int pend = (p0 + TILE_V < P) ? p0 + TILE_V : P;
  const u32 maskV = (1u << SV) - 1u;
  for (int b = tid; b < NB; b += 256) lcnt[b] = 0;
  __syncthreads();
  for (int p = p0 + tid; p < pend; p += 256) {
    const int e = pair_e[p];
    const int v = pair_v[p];
    const int s = src_v[p];
    const int b = v >> SV;
    uint2 entry;
    entry.x = ((u32)v & maskV) | ((u32)e << SV);
    entry.y = (u32)s;
    const int pos = atomicAdd(&lcnt[b], 1);
    if (pos < CAPL_V) stage[b][pos] = entry;
    else out[atomicAdd(&gcur[b], 1)] = entry;
  }
  __syncthreads();
  for (int b = tid; b < NB; b += 256) {
    const int n = lcnt[b] < CAPL_V ? lcnt[b] : CAPL_V;
    gbase[b] = atomicAdd(&gcur[b], n);
  }
  __syncthreads();
  const int wv = tid >> 6, lane = tid & 63;
  for (int b = wv; b < NB; b += 4) {
    const int n = lcnt[b] < CAPL_V ? lcnt[b] : CAPL_V;
    if (lane < n) out[gbase[b] + lane] = stage[b][lane];   // n <= 32 < 64
  }
}

__global__ void init_gcur_kernel(int* __restrict__ ge, int* __restrict__ gv,
                                 int NBE, int NBV, int capgE, int capgV) {
  const int t = (int)threadIdx.x;
  if (t < NBE) ge[t] = t * capgE;
  if (t < NBV) gv[t] = t * capgV;
}

// ---------------- bucket-local degree histogram ----------------
__global__ __launch_bounds__(256) void bucket_hist_kernel(
    const u32* __restrict__ entE, const int* __restrict__ gcurE, int* __restrict__ cnt_e,
    const uint2* __restrict__ entV, const int* __restrict__ gcurV, int* __restrict__ cnt_v,
    int NBE, int SE, int capgE, int SV, int capgV, int M, int N) {
  __shared__ int h[1024];
  const int b = (int)blockIdx.x;
  const int tid = (int)threadIdx.x;
  if (b < NBE) {
    const int nb = 1 << SE;
    for (int t = tid; t < nb; t += 256) h[t] = 0;
    __syncthreads();
    const int end = gcurE[b];
    for (int i = b * capgE + tid; i < end; i += 256)
      atomicAdd(&h[entE[i] >> 17], 1);
    __syncthreads();
    const int base = b << SE;
    for (int t = tid; t < nb; t += 256)
      if (base + t < M) cnt_e[base + t] = h[t];
  } else {
    const int bb = b - NBE;
    const int nb = 1 << SV;
    for (int t = tid; t < nb; t += 256) h[t] = 0;
    __syncthreads();
    const int end = gcurV[bb];
    const u32 mask = (1u << SV) - 1u;
    for (int i = bb * capgV + tid; i < end; i += 256)
      atomicAdd(&h[entV[i].x & mask], 1);
    __syncthreads();
    const int base = bb << SV;
    for (int t = tid; t < nb; t += 256)
      if (base + t < N) cnt_v[base + t] = h[t];
  }
}

// ---------------- pass B: unbin into final CSR (edge side) ----------------
__global__ __launch_bounds__(512) void unbin_edge_kernel(
    const u32* __restrict__ ent, const int* __restrict__ gcur,
    int* __restrict__ cur_e, int* __restrict__ edge_vtx,
    int SE, int capg) {
  const int b = blockIdx.x;
  const int end = gcur[b];
  const int ebase = b << SE;
  for (int i = b * capg + (int)threadIdx.x; i < end; i += 512) {
    const u32 w = ent[i];
    const int v = (int)(w & 0x1ffffu);
    const int e = ebase + (int)(w >> 17);
    edge_vtx[atomicAdd(&cur_e[e], 1)] = v;
  }
}

// ---------------- pass B: unbin into final CSR (vertex side) ----------------
// Writes BOTH vtx_es (for attn pass) and compact vtx_edge (for P2/P6).
__global__ __launch_bounds__(512) void unbin_vtx_kernel(
    const uint2* __restrict__ ent, const int* __restrict__ gcur,
    int* __restrict__ cur_v, int2* __restrict__ vtx_es, int* __restrict__ vtx_edge,
    const float* __restrict__ svec, const float* __restrict__ dvec,
    int SV, int capg) {
  const int b = blockIdx.x;
  const int end = gcur[b];
  const int vbase = b << SV;
  const u32 maskV = (1u << SV) - 1u;
  for (int i = b * capg + (int)threadIdx.x; i < end; i += 512) {
    const uint2 w = ent[i];
    const int v = vbase + (int)(w.x & maskV);
    const int e = (int)(w.x >> SV);
    float sc = svec[w.y] + dvec[v];
    sc = sc > 0.f ? sc : 0.2f * sc;           // leaky_relu(0.2)
    sc = fminf(fmaxf(sc, 0.001f), 5.0f);      // clip
    const int iv = atomicAdd(&cur_v[v], 1);
    vtx_es[iv] = make_int2(e, __float_as_int(__expf(sc)));
    vtx_edge[iv] = e;
  }
}

// ---------------- hierarchical scan, phase A ----------------
__global__ __launch_bounds__(1024) void blocksum_kernel(
    const int* __restrict__ cnt_e, const int* __restrict__ cnt_v,
    int* __restrict__ part, int CE, int M, int N) {
  const int b = blockIdx.x;
  const int* cnt;
  int n, chunk;
  if (b < CE) { cnt = cnt_e; n = M; chunk = b; }
  else        { cnt = cnt_v; n = N; chunk = b - CE; }
  const int i = chunk * CHUNK + (int)threadIdx.x;
  int x = (i < n) ? cnt[i] : 0;
#pragma unroll
  for (int m = 32; m >= 1; m >>= 1) x += __shfl_xor(x, m, 64);
  __shared__ int ws[16];
  if ((threadIdx.x & 63) == 0) ws[threadIdx.x >> 6] = x;
  __syncthreads();
  if (threadIdx.x == 0) {
    int t = 0;
#pragma unroll
    for (int q = 0; q < 16; ++q) t += ws[q];
    part[b] = t;
  }
}

// ---------------- phase B ----------------
__global__ __launch_bounds__(256) void partscan_kernel(
    int* __restrict__ part, int CE, int CV,
    int* __restrict__ off_e, int* __restrict__ off_v, int M, int N) {
  __shared__ int sh[256];
  const int tid = (int)threadIdx.x;
  for (int s = 0; s < 2; ++s) {
    const int base = s ? CE : 0;
    const int count = s ? CV : CE;   // both <= 256
    int x = (tid < count) ? part[base + tid] : 0;
    sh[tid] = x;
    __syncthreads();
    for (int ofs = 1; ofs < 256; ofs <<= 1) {
      int v = (tid >= ofs) ? sh[tid - ofs] : 0;
      __syncthreads();
      sh[tid] += v;
      __syncthreads();
    }
    if (tid < count) part[base + tid] = sh[tid] - x;   // exclusive
    if (tid == 0) {
      const int tot = sh[count - 1];
      if (s == 0) off_e[M] = tot; else off_v[N] = tot;
    }
    __syncthreads();
  }
}

// ---------------- phase C ----------------
__global__ __launch_bounds__(1024) void blockscan_kernel(
    const int* __restrict__ cnt_e, const int* __restrict__ cnt_v,
    const int* __restrict__ part,
    int* __restrict__ off_e, int* __restrict__ off_v,
    int* __restrict__ cur_e, int* __restrict__ cur_v,
    float* __restrict__ de_inv, float* __restrict__ dv_inv, float* __restrict__ dv_isqrt,
    int CE, int M, int N) {
  __shared__ int sh[CHUNK];
  const int b = blockIdx.x;
  const int tid = (int)threadIdx.x;
  const int* cnt;
  int n, chunk;
  int *off, *cur;
  float *i1, *i2;
  if (b < CE) { cnt = cnt_e; n = M; chunk = b;      off = off_e; cur = cur_e; i1 = de_inv; i2 = nullptr; }
  else        { cnt = cnt_v; n = N; chunk = b - CE; off = off_v; cur = cur_v; i1 = dv_inv; i2 = dv_isqrt; }
  const int i = chunk * CHUNK + tid;
  const int x = (i < n) ? cnt[i] : 0;
  sh[tid] = x;
  __syncthreads();
  for (int ofs = 1; ofs < CHUNK; ofs <<= 1) {
    int v = (tid >= ofs) ? sh[tid - ofs] : 0;
    __syncthreads();
    sh[tid] += v;
    __syncthreads();
  }
  if (i < n) {
    const int o = part[b] + sh[tid] - x;
    off[i] = o;
    cur[i] = o;              // cursor pre-initialized to offset
    const float m = (float)(x > 1 ? x : 1);
    i1[i] = 1.0f / m;
    if (i2) i2[i] = 1.0f / sqrtf(m);
  }
}

// ---------------- W split ----------------
__global__ __launch_bounds__(256) void prep_w_kernel(
    const float* __restrict__ W, u16* __restrict__ whi, u16* __restrict__ wlo) {
  const int i = (int)blockIdx.x * 256 + (int)threadIdx.x;
  if (i >= 128 * 128) return;
  u32 h, l;
  bfsplit(W[i], h, l);
  whi[i] = (u16)h;
  wlo[i] = (u16)l;
}

// ---------------- MFMA GEMM (split-bf16, 3 terms) ----------------
#define XPAD 136
__global__ __launch_bounds__(256) void gemm_mfma_kernel(
    const float* __restrict__ X,
    const u16* __restrict__ whi, const u16* __restrict__ wlo,
    const float* __restrict__ bias, const float* __restrict__ wsrc,
    const float* __restrict__ wdst, const float* __restrict__ dv_isqrt,
    u16* __restrict__ Hb, float* __restrict__ s_out, float* __restrict__ d_out,
    int N) {
  __shared__ u16 xhi[64 * XPAD];
  __shared__ u16 xlo[64 * XPAD];
  __shared__ float sred[64];
  __shared__ float dred[64];
  const int tid = (int)threadIdx.x;
  const int row0 = (int)blockIdx.x * 64;

  if (tid < 64) { sred[tid] = 0.f; dred[tid] = 0.f; }
  for (int g = tid; g < 64 * 32; g += 256) {
    const int r = g >> 5;
    const int k4 = (g & 31) << 2;
    int rr = row0 + r; if (rr >= N) rr = N - 1;
    const float4 v = *(const float4*)(X + (size_t)rr * 128 + k4);
    u32 h0, l0, h1, l1, h2, l2, h3, l3;
    bfsplit(v.x, h0, l0); bfsplit(v.y, h1, l1);
    bfsplit(v.z, h2, l2); bfsplit(v.w, h3, l3);
    *(uint2*)(xhi + r * XPAD + k4) = make_uint2(h0 | (h1 << 16), h2 | (h3 << 16));
    *(uint2*)(xlo + r * XPAD + k4) = make_uint2(l0 | (l1 << 16), l2 | (l3 << 16));
  }
  __syncthreads();

  const int wv = tid >> 6;       // wave id: col slice
  const int l  = tid & 63;
  const int lr = l & 15;         // A-row / B-col within 16
  const int lg = l >> 4;         // k-group
  const int cb = wv * 32;

  f32x4 zero = {0.f, 0.f, 0.f, 0.f};
  f32x4 acc[4][2];
#pragma unroll
  for (int rt = 0; rt < 4; ++rt) { acc[rt][0] = zero; acc[rt][1] = zero; }

#pragma unroll
  for (int kk = 0; kk < 4; ++kk) {
    const int kof = kk * 32 + lg * 8;
    const bf16x8 bh0 = *(const bf16x8*)(whi + (size_t)(cb + lr) * 128 + kof);
    const bf16x8 bh1 = *(const bf16x8*)(whi + (size_t)(cb + 16 + lr) * 128 + kof);
    const bf16x8 bl0 = *(const bf16x8*)(wlo + (size_t)(cb + lr) * 128 + kof);
    const bf16x8 bl1 = *(const bf16x8*)(wlo + (size_t)(cb + 16 + lr) * 128 + kof);
#pragma unroll
    for (int rt = 0; rt < 4; ++rt) {
      const bf16x8 ah = *(const bf16x8*)(xhi + (rt * 16 + lr) * XPAD + kof);
      const bf16x8 al = *(const bf16x8*)(xlo + (rt * 16 + lr) * XPAD + kof);
      acc[rt][0] = __builtin_amdgcn_mfma_f32_16x16x32_bf16(ah, bh0, acc[rt][0], 0, 0, 0);
      acc[rt][1] = __builtin_amdgcn_mfma_f32_16x16x32_bf16(ah, bh1, acc[rt][1], 0, 0, 0);
      acc[rt][0] = __builtin_amdgcn_mfma_f32_16x16x32_bf16(al, bh0, acc[rt][0], 0, 0, 0);
      acc[rt][1] = __builtin_amdgcn_mfma_f32_16x16x32_bf16(al, bh1, acc[rt][1], 0, 0, 0);
      acc[rt][0] = __builtin_amdgcn_mfma_f32_16x16x32_bf16(ah, bl0, acc[rt][0], 0, 0, 0);
      acc[rt][1] = __builtin_amdgcn_mfma_f32_16x16x32_bf16(ah, bl1, acc[rt][1], 0, 0, 0);
    }
  }

  const int c0 = cb + lr, c1 = cb + 16 + lr;
  const float bb0 = bias[c0], bb1 = bias[c1];
  const float ws0 = wsrc[c0], ws1 = wsrc[c1];
  const float wd0 = wdst[c0], wd1 = wdst[c1];
#pragma unroll
  for (int rt = 0; rt < 4; ++rt) {
#pragma unroll
    for (int j = 0; j < 4; ++j) {
      const int rl = rt * 16 + lg * 4 + j;
      const int row = row0 + rl;
      const float h0 = acc[rt][0][j] + bb0;
      const float h1 = acc[rt][1][j] + bb1;
      float sp = h0 * ws0 + h1 * ws1;
      float dp = h0 * wd0 + h1 * wd1;
#pragma unroll
      for (int m = 1; m <= 8; m <<= 1) {
        sp += __shfl_xor(sp, m, 64);
        dp += __shfl_xor(dp, m, 64);
      }
      if (lr == 0) { atomicAdd(&sred[rl], sp); atomicAdd(&dred[rl], dp); }
      if (row < N) {
        const float sc = dv_isqrt[row];
        Hb[(size_t)row * 128 + c0] = (u16)bf16rne(h0 * sc);
        Hb[(size_t)row * 128 + c1] = (u16)bf16rne(h1 * sc);
      }
    }
  }
  __syncthreads();
  if (tid < 64) {
    const int row = row0 + tid;
    if (row < N) { s_out[row] = sred[tid]; d_out[row] = dred[tid]; }
  }
}

#define ACC8(r, p)                                         \
  a[0] += bflo((r).x) * (p); a[1] += bfhi((r).x) * (p);    \
  a[2] += bflo((r).y) * (p); a[3] += bfhi((r).y) * (p);    \
  a[4] += bflo((r).z) * (p); a[5] += bfhi((r).z) * (p);    \
  a[6] += bflo((r).w) * (p); a[7] += bfhi((r).w) * (p);

// ---------------- M-direction segment sum (P1/P3/P5), 8-deep clamped ----------------
// Mean de = 32 -> window 32: quarter q owns {t0+q, +4, ..., +28}; OOR slots
// clamp to last index, weight 0 -> EVERY window issues 8 loads per lane
// (8-deep MLP; dummies hit a hot line). Full 256B row: 16 lanes x uint4.
__global__ __launch_bounds__(256) void seg_pass_kernel(
    const u16* __restrict__ src, u16* __restrict__ dst,
    const int* __restrict__ off, const int* __restrict__ lst,
    const float* __restrict__ post_scale, int nseg) {
  const int seg = blockIdx.x * 4 + ((int)threadIdx.x >> 6);
  if (seg >= nseg) return;
  const int lane = (int)threadIdx.x & 63;
  const int q = lane >> 4;
  const int cl = lane & 15;
  const int beg = off[seg], end = off[seg + 1];
  const int last = end - 1;
  float a[8] = {};
  for (int t0 = beg + q; t0 < end; t0 += 32) {
    int jj[8];
    float ww[8];
    jj[0] = lst[t0];
    ww[0] = 1.f;
#pragma unroll
    for (int u = 1; u < 8; ++u) {
      const int t = t0 + 4 * u;
      jj[u] = lst[t <= last ? t : last];
      ww[u] = t <= last ? 1.f : 0.f;
    }
    uint4 rr[8];
#pragma unroll
    for (int u = 0; u < 8; ++u)
      rr[u] = *(const uint4*)(src + (size_t)jj[u] * 128 + cl * 8);
#pragma unroll
    for (int u = 0; u < 8; ++u) {
      const uint4 r = rr[u];
      const float p = ww[u];
      ACC8(r, p)
    }
  }
#pragma unroll
  for (int k = 0; k < 8; ++k) {
    a[k] += __shfl_xor(a[k], 16, 64);
    a[k] += __shfl_xor(a[k], 32, 64);
  }
  if (q != 0) return;
  const float ps = post_scale[seg];
  uint4 pk;
  pk.x = packbf(a[0] * ps, a[1] * ps); pk.y = packbf(a[2] * ps, a[3] * ps);
  pk.z = packbf(a[4] * ps, a[5] * ps); pk.w = packbf(a[6] * ps, a[7] * ps);
  *(uint4*)(dst + (size_t)seg * 128 + cl * 8) = pk;
}

// ---------------- N-direction segment sum (P2/P6), 4-deep clamped ----------------
// Mean dv = 16 -> window 16 matches; deeper would be mostly dummy loads.
// final_mode: ELU via __expf + nontemporal f32 store. mode 0: bf16 pack.
__global__ __launch_bounds__(256) void segn_pass_kernel(
    const u16* __restrict__ src, void* __restrict__ dst,
    const int* __restrict__ off, const int* __restrict__ lst,
    const float* __restrict__ post_scale, int nseg, int final_mode) {
  const int seg = blockIdx.x * 4 + ((int)threadIdx.x >> 6);
  if (seg >= nseg) return;
  const int lane = (int)threadIdx.x & 63;
  const int q = lane >> 4;
  const int cl = lane & 15;
  const int beg = off[seg], end = off[seg + 1];
  const int last = end - 1;
  float a[8] = {};
  for (int t0 = beg + q; t0 < end; t0 += 16) {
    const int t1 = t0 + 4, t2 = t0 + 8, t3 = t0 + 12;
    const int j0 = lst[t0];
    const int j1 = lst[t1 <= last ? t1 : last];
    const int j2 = lst[t2 <= last ? t2 : last];
    const int j3 = lst[t3 <= last ? t3 : last];
    const float w1 = t1 <= last ? 1.f : 0.f;
    const float w2 = t2 <= last ? 1.f : 0.f;
    const float w3 = t3 <= last ? 1.f : 0.f;
    const uint4 r0 = *(const uint4*)(src + (size_t)j0 * 128 + cl * 8);
    const uint4 r1 = *(const uint4*)(src + (size_t)j1 * 128 + cl * 8);
    const uint4 r2 = *(const uint4*)(src + (size_t)j2 * 128 + cl * 8);
    const uint4 r3 = *(const uint4*)(src + (size_t)j3 * 128 + cl * 8);
    ACC8(r0, 1.0f) ACC8(r1, w1) ACC8(r2, w2) ACC8(r3, w3)
  }
#pragma unroll
  for (int k = 0; k < 8; ++k) {
    a[k] += __shfl_xor(a[k], 16, 64);
    a[k] += __shfl_xor(a[k], 32, 64);
  }
  if (q != 0) return;
  const float ps = post_scale[seg];
#pragma unroll
  for (int k = 0; k < 8; ++k) a[k] *= ps;
  if (final_mode) {
#pragma unroll
    for (int k = 0; k < 8; ++k) a[k] = a[k] > 0.f ? a[k] : __expf(a[k]) - 1.0f;
    float* o = (float*)dst + (size_t)seg * 128 + cl * 8;
    f32x4 v0 = {a[0], a[1], a[2], a[3]};
    f32x4 v1 = {a[4], a[5], a[6], a[7]};
    __builtin_nontemporal_store(v0, (f32x4*)o);
    __builtin_nontemporal_store(v1, (f32x4*)(o + 4));
  } else {
    uint4 pk;
    pk.x = packbf(a[0], a[1]); pk.y = packbf(a[2], a[3]);
    pk.z = packbf(a[4], a[5]); pk.w = packbf(a[6], a[7]);
    *(uint4*)((u16*)dst + (size_t)seg * 128 + cl * 8) = pk;
  }
}

// ---------------- attention e2v (P4), 4-deep clamped ----------------
__global__ __launch_bounds__(256) void attn_pass_kernel(
    const u16* __restrict__ src, u16* __restrict__ dst,
    const int* __restrict__ off, const int2* __restrict__ lst_es, int nseg) {
  const int seg = blockIdx.x * 4 + ((int)threadIdx.x >> 6);
  if (seg >= nseg) return;
  const int lane = (int)threadIdx.x & 63;
  const int q = lane >> 4;
  const int cl = lane & 15;
  const int beg = off[seg], end = off[seg + 1];
  const int last = end - 1;
  float a[8] = {};
  float den = 0.f;
  for (int t0 = beg + q; t0 < end; t0 += 16) {
    const int t1 = t0 + 4, t2 = t0 + 8, t3 = t0 + 12;
    const int2 e0 = lst_es[t0];
    const int2 e1 = lst_es[t1 <= last ? t1 : last];
    const int2 e2 = lst_es[t2 <= last ? t2 : last];
    const int2 e3 = lst_es[t3 <= last ? t3 : last];
    const float s0 = __int_as_float(e0.y);
    const float s1 = t1 <= last ? __int_as_float(e1.y) : 0.f;
    const float s2 = t2 <= last ? __int_as_float(e2.y) : 0.f;
    const float s3 = t3 <= last ? __int_as_float(e3.y) : 0.f;
    const uint4 r0 = *(const uint4*)(src + (size_t)e0.x * 128 + cl * 8);
    const uint4 r1 = *(const uint4*)(src + (size_t)e1.x * 128 + cl * 8);
    const uint4 r2 = *(const uint4*)(src + (size_t)e2.x * 128 + cl * 8);
    const uint4 r3 = *(const uint4*)(src + (size_t)e3.x * 128 + cl * 8);
    ACC8(r0, s0) ACC8(r1, s1) ACC8(r2, s2) ACC8(r3, s3)
    den += s0 + s1 + s2 + s3;
  }
#pragma unroll
  for (int k = 0; k < 8; ++k) {
    a[k] += __shfl_xor(a[k], 16, 64);
    a[k] += __shfl_xor(a[k], 32, 64);
  }
  den += __shfl_xor(den, 16, 64);
  den += __shfl_xor(den, 32, 64);
  const float inv = (end > beg) ? 1.0f / den : 0.0f;
  if (q != 0) return;
  uint4 pk;
  pk.x = packbf(a[0] * inv, a[1] * inv); pk.y = packbf(a[2] * inv, a[3] * inv);
  pk.z = packbf(a[4] * inv, a[5] * inv); pk.w = packbf(a[6] * inv, a[7] * inv);
  *(uint4*)(dst + (size_t)seg * 128 + cl * 8) = pk;
}

extern "C" void kernel_launch(void* const* d_in, const int* in_sizes, int n_in,
                              void* d_out, int out_size, void* d_ws, size_t ws_size,
                              hipStream_t stream) {
  const float* X      = (const float*)d_in[0];
  const int*   pair_v = (const int*)d_in[1];
  const int*   pair_e = (const int*)d_in[2];
  const int*   src_v  = (const int*)d_in[3];
  const float* W      = (const float*)d_in[4];
  const float* bias   = (const float*)d_in[5];
  const float* wsrc   = (const float*)d_in[6];
  const float* wdst   = (const float*)d_in[7];

  const int N = in_sizes[0] / 128;
  const int P = in_sizes[1];
  const int M = M_EDGES;   // fixed by problem definition (pair_e in [0, 50000))
  const int CE = (M + CHUNK - 1) / CHUNK;   // <=256 for partscan
  const int CV = (N + CHUNK - 1) / CHUNK;   // <=256 for partscan

  int SE = 8;
  while ((((M - 1) >> SE) + 1) > NBMAX) ++SE;
  const int NBE = ((M - 1) >> SE) + 1;
  int SV = 9;
  while ((((N - 1) >> SV) + 1) > NBMAX) ++SV;
  const int NBV = ((N - 1) >> SV) + 1;
  const int capgE = P / NBE + P / (NBE * 8) + 256;
  const int capgV = P / NBV + P / (NBV * 8) + 256;

  char* w = (char*)d_ws;
  auto alloc = [&](size_t bytes) -> char* {
    char* p = w;
    w += (bytes + 255) & ~(size_t)255;
    return p;
  };
  int*   cnt_e     = (int*)alloc((size_t)M * 4);
  int*   cnt_v     = (int*)alloc((size_t)N * 4);
  int*   cur_e     = (int*)alloc((size_t)M * 4);
  int*   cur_v     = (int*)alloc((size_t)N * 4);
  int*   part      = (int*)alloc((size_t)(CE + CV) * 4);
  int*   edge_off  = (int*)alloc((size_t)(M + 1) * 4);
  int*   vtx_off   = (int*)alloc((size_t)(N + 1) * 4);
  float* de_inv    = (float*)alloc((size_t)M * 4);
  float* dv_inv    = (float*)alloc((size_t)N * 4);
  float* dv_isqrt  = (float*)alloc((size_t)N * 4);
  float* svec      = (float*)alloc((size_t)N * 4);
  float* dvec      = (float*)alloc((size_t)N * 4);
  int*   edge_vtx  = (int*)alloc((size_t)P * 4);
  int2*  vtx_es    = (int2*)alloc((size_t)P * 8);
  int*   vtx_edge  = (int*)alloc((size_t)P * 4);
  u16*   bufN      = (u16*)alloc((size_t)N * 128 * 2);  // Hs -> Hs2 -> Xv1 (bf16)
  u16*   bufM      = (u16*)alloc((size_t)M * 128 * 2);  // Xe -> Xe1 -> Xe2 (bf16)
  u32*   binE      = (u32*)alloc((size_t)NBE * capgE * 4);
  uint2* binV      = (uint2*)alloc((size_t)NBV * capgV * 8);
  int*   gcur_e    = (int*)alloc((size_t)NBE * 4);
  int*   gcur_v    = (int*)alloc((size_t)NBV * 4);
  u16*   whi_g     = (u16*)alloc((size_t)128 * 128 * 2);
  u16*   wlo_g     = (u16*)alloc((size_t)128 * 128 * 2);

  prep_w_kernel<<<64, 256, 0, stream>>>(W, whi_g, wlo_g);
  init_gcur_kernel<<<1, 256, 0, stream>>>(gcur_e, gcur_v, NBE, NBV, capgE, capgV);
  bin_edge_kernel<<<(P + TILE_E - 1) / TILE_E, 256, 0, stream>>>(
      pair_e, pair_v, binE, gcur_e, P, SE, NBE);
  bin_vtx_kernel<<<(P + TILE_V - 1) / TILE_V, 256, 0, stream>>>(
      pair_e, pair_v, src_v, binV, gcur_v, P, SV, NBV);
  bucket_hist_kernel<<<NBE + NBV, 256, 0, stream>>>(
      binE, gcur_e, cnt_e, binV, gcur_v, cnt_v, NBE, SE, capgE, SV, capgV, M, N);
  blocksum_kernel<<<CE + CV, 1024, 0, stream>>>(cnt_e, cnt_v, part, CE, M, N);
  partscan_kernel<<<1, 256, 0, stream>>>(part, CE, CV, edge_off, vtx_off, M, N);
  blockscan_kernel<<<CE + CV, 1024, 0, stream>>>(cnt_e, cnt_v, part, edge_off, vtx_off,
                                                 cur_e, cur_v, de_inv, dv_inv, dv_isqrt,
                                                 CE, M, N);
  gemm_mfma_kernel<<<(N + 63) / 64, 256, 0, stream>>>(X, whi_g, wlo_g, bias, wsrc, wdst,
                                                      dv_isqrt, bufN, svec, dvec, N);
  unbin_edge_kernel<<<NBE, 512, 0, stream>>>(binE, gcur_e, cur_e, edge_vtx, SE, capgE);
  unbin_vtx_kernel<<<NBV, 512, 0, stream>>>(binV, gcur_v, cur_v, vtx_es, vtx_edge,
                                            svec, dvec, SV, capgV);

  const int gm = (M + 3) / 4;
  const int gn = (N + 3) / 4;
  // P1: Xe  = de_inv * sum Hs[v]          (dv_isqrt folded into Hs at GEMM)
  seg_pass_kernel<<<gm, 256, 0, stream>>>(bufN, bufM, edge_off, edge_vtx, de_inv, M);
  // P2: Hs2 = dv_isqrt * sum Xe[e]
  segn_pass_kernel<<<gn, 256, 0, stream>>>(bufM, bufN, vtx_off, vtx_edge, dv_isqrt, N, 0);
  // P3: Xe1 = de_inv * sum Hs2[v]
  seg_pass_kernel<<<gm, 256, 0, stream>>>(bufN, bufM, edge_off, edge_vtx, de_inv, M);
  // P4: Xv1 = softmax-weighted sum of Xe1[e]
  attn_pass_kernel<<<gn, 256, 0, stream>>>(bufM, bufN, vtx_off, vtx_es, N);
  // P5: Xe2 = de_inv * sum Xv1[v]
  seg_pass_kernel<<<gm, 256, 0, stream>>>(bufN, bufM, edge_off, edge_vtx, de_inv, M);
  // P6: out = elu(dv_inv * sum Xe2[e])  -> fp32 nontemporal
  segn_pass_kernel<<<gn, 256, 0, stream>>>(bufM, d_out, vtx_off, vtx_edge, dv_inv, N, 1);
}

// Round 9
// 565.964 us; speedup vs baseline: 1.2210x; 1.0905x over previous
//
#include <hip/hip_runtime.h>
#include <math.h>

#define M_EDGES 50000
#define CHUNK 1024

// binned-scatter parameters
#define NBMAX 200      // max buckets per side (LDS arrays sized to this)
#define TILE_E 4096    // pairs per block, edge-bin pass
#define TILE_V 4096    // pairs per block, vtx-bin pass
#define CAPL_E 44      // LDS staging capacity per bucket (lambda ~20.9)
#define CAPL_V 32      // LDS staging capacity per bucket (lambda ~20.9)
#define STAGEE 9472    // unbin_edge LDS slice capacity (>= capgE ~9439)
#define STAGEV 5888    // unbin_vtx LDS half-slice capacity (mean 4096, +28 sd)

typedef unsigned int u32;
typedef unsigned short u16;
typedef float f32x4 __attribute__((ext_vector_type(4)));
typedef short bf16x8 __attribute__((ext_vector_type(8)));

__device__ __forceinline__ float bflo(u32 u) { return __uint_as_float(u << 16); }
__device__ __forceinline__ float bfhi(u32 u) { return __uint_as_float(u & 0xffff0000u); }
__device__ __forceinline__ u32 packbf(float x, float y) {   // RNE both halves
  u32 a = __float_as_uint(x); a += 0x7fffu + ((a >> 16) & 1u);
  u32 b = __float_as_uint(y); b += 0x7fffu + ((b >> 16) & 1u);
  return (a >> 16) | (b & 0xffff0000u);
}
__device__ __forceinline__ u32 bf16rne(float x) {
  u32 a = __float_as_uint(x);
  a += 0x7fffu + ((a >> 16) & 1u);
  return a >> 16;
}
// split f into bf16 hi + bf16 lo with f ~= hi + lo (error ~2^-18 rel)
__device__ __forceinline__ void bfsplit(float f, u32& h, u32& l) {
  h = bf16rne(f);
  const float hf = __uint_as_float(h << 16);
  l = bf16rne(f - hf);
}

// ---------------- binned scatter, pass A (edge side) ----------------
// Entry: v (17b) | e_lo (<<17).
__global__ __launch_bounds__(256) void bin_edge_kernel(
    const int* __restrict__ pair_e, const int* __restrict__ pair_v,
    u32* __restrict__ out, int* __restrict__ gcur,
    int P, int SE, int NB) {
  __shared__ int lcnt[NBMAX];
  __shared__ int gbase[NBMAX];
  __shared__ u32 stage[NBMAX][CAPL_E];
  const int tid = (int)threadIdx.x;
  const int p0 = blockIdx.x * TILE_E;
  const int pend = (p0 + TILE_E < P) ? p0 + TILE_E : P;
  const u32 maskE = (1u << SE) - 1u;
  for (int b = tid; b < NB; b += 256) lcnt[b] = 0;
  __syncthreads();
  for (int p = p0 + tid; p < pend; p += 256) {
    const int e = pair_e[p];
    const int v = pair_v[p];
    const int b = e >> SE;
    const u32 entry = (u32)v | (((u32)e & maskE) << 17);
    const int pos = atomicAdd(&lcnt[b], 1);
    if (pos < CAPL_E) stage[b][pos] = entry;
    else out[atomicAdd(&gcur[b], 1)] = entry;   // rare overflow: direct append
  }
  __syncthreads();
  for (int b = tid; b < NB; b += 256) {
    const int n = lcnt[b] < CAPL_E ? lcnt[b] : CAPL_E;
    gbase[b] = atomicAdd(&gcur[b], n);
  }
  __syncthreads();
  const int wv = tid >> 6, lane = tid & 63;
  for (int b = wv; b < NB; b += 4) {
    const int n = lcnt[b] < CAPL_E ? lcnt[b] : CAPL_E;
    if (lane < n) out[gbase[b] + lane] = stage[b][lane];   // n <= 44 < 64
  }
}

// ---------------- binned scatter, pass A (vertex side) ----------------
// Entry: {v_lo | e<<SV, src}.
__global__ __launch_bounds__(256) void bin_vtx_kernel(
    const int* __restrict__ pair_e, const int* __restrict__ pair_v,
    const int* __restrict__ src_v,
    uint2* __restrict__ out, int* __restrict__ gcur,
    int P, int SV, int NB) {
  __shared__ int lcnt[NBMAX];
  __shared__ int gbase[NBMAX];
  __shared__ uint2 stage[NBMAX][CAPL_V];
  const int tid = (int)threadIdx.x;
  const int p0 = blockIdx.x * TILE_V;
  const int pend = (p0 + TILE_V < P) ? p0 + TILE_V : P;
  const u32 maskV = (1u << SV) - 1u;
  for (int b = tid; b < NB; b += 256) lcnt[b] = 0;
  __syncthreads();
  for (int p = p0 + tid; p < pend; p += 256) {
    const int e = pair_e[p];
    const int v = pair_v[p];
    const int s = src_v[p];
    const int b = v >> SV;
    uint2 entry;
    entry.x = ((u32)v & maskV) | ((u32)e << SV);
    entry.y = (u32)s;
    const int pos = atomicAdd(&lcnt[b], 1);
    if (pos < CAPL_V) stage[b][pos] = entry;
    else out[atomicAdd(&gcur[b], 1)] = entry;
  }
  __syncthreads();
  for (int b = tid; b < NB; b += 256) {
    const int n = lcnt[b] < CAPL_V ? lcnt[b] : CAPL_V;
    gbase[b] = atomicAdd(&gcur[b], n);
  }
  __syncthreads();
  const int wv = tid >> 6, lane = tid & 63;
  for (int b = wv; b < NB; b += 4) {
    const int n = lcnt[b] < CAPL_V ? lcnt[b] : CAPL_V;
    if (lane < n) out[gbase[b] + lane] = stage[b][lane];   // n <= 32 < 64
  }
}

__global__ void init_gcur_kernel(int* __restrict__ ge, int* __restrict__ gv,
                                 int NBE, int NBV, int capgE, int capgV) {
  const int t = (int)threadIdx.x;
  if (t < NBE) ge[t] = t * capgE;
  if (t < NBV) gv[t] = t * capgV;
}

// ---------------- bucket-local degree histogram ----------------
__global__ __launch_bounds__(256) void bucket_hist_kernel(
    const u32* __restrict__ entE, const int* __restrict__ gcurE, int* __restrict__ cnt_e,
    const uint2* __restrict__ entV, const int* __restrict__ gcurV, int* __restrict__ cnt_v,
    int NBE, int SE, int capgE, int SV, int capgV, int M, int N) {
  __shared__ int h[1024];
  const int b = (int)blockIdx.x;
  const int tid = (int)threadIdx.x;
  if (b < NBE) {
    const int nb = 1 << SE;
    for (int t = tid; t < nb; t += 256) h[t] = 0;
    __syncthreads();
    const int end = gcurE[b];
    for (int i = b * capgE + tid; i < end; i += 256)
      atomicAdd(&h[entE[i] >> 17], 1);
    __syncthreads();
    const int base = b << SE;
    for (int t = tid; t < nb; t += 256)
      if (base + t < M) cnt_e[base + t] = h[t];
  } else {
    const int bb = b - NBE;
    const int nb = 1 << SV;
    for (int t = tid; t < nb; t += 256) h[t] = 0;
    __syncthreads();
    const int end = gcurV[bb];
    const u32 mask = (1u << SV) - 1u;
    for (int i = bb * capgV + tid; i < end; i += 256)
      atomicAdd(&h[entV[i].x & mask], 1);
    __syncthreads();
    const int base = bb << SV;
    for (int t = tid; t < nb; t += 256)
      if (base + t < N) cnt_v[base + t] = h[t];
  }
}

// ---------------- pass B: unbin into final CSR (edge side) ----------------
// LDS-staged: build the bucket's contiguous CSR slice in LDS with local
// cursors, then stream it out coalesced. Kills the 64B-line write
// amplification of the random 4B scatter (partial dirty lines evicted
// repeatedly under L2 pressure).
__global__ __launch_bounds__(512) void unbin_edge_kernel(
    const u32* __restrict__ ent, const int* __restrict__ gcur,
    const int* __restrict__ off_e, int* __restrict__ edge_vtx,
    int SE, int capg, int M) {
  __shared__ int stage[STAGEE];
  __shared__ int ecur[512];
  const int b = blockIdx.x;
  const int tid = (int)threadIdx.x;
  const int ebase = b << SE;
  const int ne = 1 << SE;
  const int elim = (ebase + ne < M) ? ebase + ne : M;
  const int sbeg = off_e[ebase];
  const int send = off_e[elim];
  for (int t = tid; t < ne; t += 512)
    ecur[t] = ((ebase + t) < M ? off_e[ebase + t] : send) - sbeg;
  __syncthreads();
  const int end = gcur[b];
  for (int i = b * capg + tid; i < end; i += 512) {
    const u32 w = ent[i];
    const int v = (int)(w & 0x1ffffu);
    const int le = (int)(w >> 17);
    const int pos = atomicAdd(&ecur[le], 1);
    if (pos < STAGEE) stage[pos] = v;
    else edge_vtx[sbeg + pos] = v;   // statistically-never overflow fallback
  }
  __syncthreads();
  const int len = send - sbeg;
  const int lim = len < STAGEE ? len : STAGEE;
  for (int i = tid; i < lim; i += 512)
    edge_vtx[sbeg + i] = stage[i];
}

// ---------------- pass B: unbin into final CSR (vertex side) ----------------
// Two sub-passes over 256-vertex halves (whole slice ~75KB > LDS static cap);
// each sub-pass re-scans the L2-hot bin region, stages {e, es} in LDS, then
// writes BOTH vtx_es and vtx_edge coalesced from the same staging.
__global__ __launch_bounds__(512) void unbin_vtx_kernel(
    const uint2* __restrict__ ent, const int* __restrict__ gcur,
    const int* __restrict__ off_v, int2* __restrict__ vtx_es, int* __restrict__ vtx_edge,
    const float* __restrict__ svec, const float* __restrict__ dvec,
    int SV, int capg, int N) {
  __shared__ int2 stage[STAGEV];
  __shared__ int vcur[512];
  const int b = blockIdx.x;
  const int tid = (int)threadIdx.x;
  const int vbase = b << SV;
  const u32 maskV = (1u << SV) - 1u;
  const int end = gcur[b];
  const int half = 1 << (SV - 1);
  for (int s = 0; s < 2; ++s) {
    const int v0 = vbase + s * half;
    if (v0 >= N) break;
    const int vlim = (v0 + half < N) ? v0 + half : N;
    const int nv = vlim - v0;
    const int sbeg = off_v[v0];
    const int send = off_v[vlim];
    for (int t = tid; t < nv; t += 512)
      vcur[t] = off_v[v0 + t] - sbeg;
    __syncthreads();
    for (int i = b * capg + tid; i < end; i += 512) {
      const uint2 w = ent[i];
      const int v = vbase + (int)(w.x & maskV);
      const u32 lv = (u32)(v - v0);
      if (lv < (u32)nv) {
        const int e = (int)(w.x >> SV);
        float sc = svec[w.y] + dvec[v];
        sc = sc > 0.f ? sc : 0.2f * sc;           // leaky_relu(0.2)
        sc = fminf(fmaxf(sc, 0.001f), 5.0f);      // clip
        const int2 val = make_int2(e, __float_as_int(__expf(sc)));
        const int pos = atomicAdd(&vcur[lv], 1);
        if (pos < STAGEV) stage[pos] = val;
        else { vtx_es[sbeg + pos] = val; vtx_edge[sbeg + pos] = e; }
      }
    }
    __syncthreads();
    const int len = send - sbeg;
    const int lim = len < STAGEV ? len : STAGEV;
    for (int i = tid; i < lim; i += 512) {
      const int2 val = stage[i];
      vtx_es[sbeg + i] = val;
      vtx_edge[sbeg + i] = val.x;
    }
    __syncthreads();
  }
}

// ---------------- hierarchical scan, phase A ----------------
__global__ __launch_bounds__(1024) void blocksum_kernel(
    const int* __restrict__ cnt_e, const int* __restrict__ cnt_v,
    int* __restrict__ part, int CE, int M, int N) {
  const int b = blockIdx.x;
  const int* cnt;
  int n, chunk;
  if (b < CE) { cnt = cnt_e; n = M; chunk = b; }
  else        { cnt = cnt_v; n = N; chunk = b - CE; }
  const int i = chunk * CHUNK + (int)threadIdx.x;
  int x = (i < n) ? cnt[i] : 0;
#pragma unroll
  for (int m = 32; m >= 1; m >>= 1) x += __shfl_xor(x, m, 64);
  __shared__ int ws[16];
  if ((threadIdx.x & 63) == 0) ws[threadIdx.x >> 6] = x;
  __syncthreads();
  if (threadIdx.x == 0) {
    int t = 0;
#pragma unroll
    for (int q = 0; q < 16; ++q) t += ws[q];
    part[b] = t;
  }
}

// ---------------- phase B ----------------
__global__ __launch_bounds__(256) void partscan_kernel(
    int* __restrict__ part, int CE, int CV,
    int* __restrict__ off_e, int* __restrict__ off_v, int M, int N) {
  __shared__ int sh[256];
  const int tid = (int)threadIdx.x;
  for (int s = 0; s < 2; ++s) {
    const int base = s ? CE : 0;
    const int count = s ? CV : CE;   // both <= 256
    int x = (tid < count) ? part[base + tid] : 0;
    sh[tid] = x;
    __syncthreads();
    for (int ofs = 1; ofs < 256; ofs <<= 1) {
      int v = (tid >= ofs) ? sh[tid - ofs] : 0;
      __syncthreads();
      sh[tid] += v;
      __syncthreads();
    }
    if (tid < count) part[base + tid] = sh[tid] - x;   // exclusive
    if (tid == 0) {
      const int tot = sh[count - 1];
      if (s == 0) off_e[M] = tot; else off_v[N] = tot;
    }
    __syncthreads();
  }
}

// ---------------- phase C ----------------
__global__ __launch_bounds__(1024) void blockscan_kernel(
    const int* __restrict__ cnt_e, const int* __restrict__ cnt_v,
    const int* __restrict__ part,
    int* __restrict__ off_e, int* __restrict__ off_v,
    float* __restrict__ de_inv, float* __restrict__ dv_inv, float* __restrict__ dv_isqrt,
    int CE, int M, int N) {
  __shared__ int sh[CHUNK];
  const int b = blockIdx.x;
  const int tid = (int)threadIdx.x;
  const int* cnt;
  int n, chunk;
  int *off;
  float *i1, *i2;
  if (b < CE) { cnt = cnt_e; n = M; chunk = b;      off = off_e; i1 = de_inv; i2 = nullptr; }
  else        { cnt = cnt_v; n = N; chunk = b - CE; off = off_v; i1 = dv_inv; i2 = dv_isqrt; }
  const int i = chunk * CHUNK + tid;
  const int x = (i < n) ? cnt[i] : 0;
  sh[tid] = x;
  __syncthreads();
  for (int ofs = 1; ofs < CHUNK; ofs <<= 1) {
    int v = (tid >= ofs) ? sh[tid - ofs] : 0;
    __syncthreads();
    sh[tid] += v;
    __syncthreads();
  }
  if (i < n) {
    const int o = part[b] + sh[tid] - x;
    off[i] = o;
    const float m = (float)(x > 1 ? x : 1);
    i1[i] = 1.0f / m;
    if (i2) i2[i] = 1.0f / sqrtf(m);
  }
}

// ---------------- W split ----------------
__global__ __launch_bounds__(256) void prep_w_kernel(
    const float* __restrict__ W, u16* __restrict__ whi, u16* __restrict__ wlo) {
  const int i = (int)blockIdx.x * 256 + (int)threadIdx.x;
  if (i >= 128 * 128) return;
  u32 h, l;
  bfsplit(W[i], h, l);
  whi[i] = (u16)h;
  wlo[i] = (u16)l;
}

// ---------------- MFMA GEMM (split-bf16, 3 terms) ----------------
#define XPAD 136
__global__ __launch_bounds__(256) void gemm_mfma_kernel(
    const float* __restrict__ X,
    const u16* __restrict__ whi, const u16* __restrict__ wlo,
    const float* __restrict__ bias, const float* __restrict__ wsrc,
    const float* __restrict__ wdst, const float* __restrict__ dv_isqrt,
    u16* __restrict__ Hb, float* __restrict__ s_out, float* __restrict__ d_out,
    int N) {
  __shared__ u16 xhi[64 * XPAD];
  __shared__ u16 xlo[64 * XPAD];
  __shared__ float sred[64];
  __shared__ float dred[64];
  const int tid = (int)threadIdx.x;
  const int row0 = (int)blockIdx.x * 64;

  if (tid < 64) { sred[tid] = 0.f; dred[tid] = 0.f; }
  for (int g = tid; g < 64 * 32; g += 256) {
    const int r = g >> 5;
    const int k4 = (g & 31) << 2;
    int rr = row0 + r; if (rr >= N) rr = N - 1;
    const float4 v = *(const float4*)(X + (size_t)rr * 128 + k4);
    u32 h0, l0, h1, l1, h2, l2, h3, l3;
    bfsplit(v.x, h0, l0); bfsplit(v.y, h1, l1);
    bfsplit(v.z, h2, l2); bfsplit(v.w, h3, l3);
    *(uint2*)(xhi + r * XPAD + k4) = make_uint2(h0 | (h1 << 16), h2 | (h3 << 16));
    *(uint2*)(xlo + r * XPAD + k4) = make_uint2(l0 | (l1 << 16), l2 | (l3 << 16));
  }
  __syncthreads();

  const int wv = tid >> 6;       // wave id: col slice
  const int l  = tid & 63;
  const int lr = l & 15;         // A-row / B-col within 16
  const int lg = l >> 4;         // k-group
  const int cb = wv * 32;

  f32x4 zero = {0.f, 0.f, 0.f, 0.f};
  f32x4 acc[4][2];
#pragma unroll
  for (int rt = 0; rt < 4; ++rt) { acc[rt][0] = zero; acc[rt][1] = zero; }

#pragma unroll
  for (int kk = 0; kk < 4; ++kk) {
    const int kof = kk * 32 + lg * 8;
    const bf16x8 bh0 = *(const bf16x8*)(whi + (size_t)(cb + lr) * 128 + kof);
    const bf16x8 bh1 = *(const bf16x8*)(whi + (size_t)(cb + 16 + lr) * 128 + kof);
    const bf16x8 bl0 = *(const bf16x8*)(wlo + (size_t)(cb + lr) * 128 + kof);
    const bf16x8 bl1 = *(const bf16x8*)(wlo + (size_t)(cb + 16 + lr) * 128 + kof);
#pragma unroll
    for (int rt = 0; rt < 4; ++rt) {
      const bf16x8 ah = *(const bf16x8*)(xhi + (rt * 16 + lr) * XPAD + kof);
      const bf16x8 al = *(const bf16x8*)(xlo + (rt * 16 + lr) * XPAD + kof);
      acc[rt][0] = __builtin_amdgcn_mfma_f32_16x16x32_bf16(ah, bh0, acc[rt][0], 0, 0, 0);
      acc[rt][1] = __builtin_amdgcn_mfma_f32_16x16x32_bf16(ah, bh1, acc[rt][1], 0, 0, 0);
      acc[rt][0] = __builtin_amdgcn_mfma_f32_16x16x32_bf16(al, bh0, acc[rt][0], 0, 0, 0);
      acc[rt][1] = __builtin_amdgcn_mfma_f32_16x16x32_bf16(al, bh1, acc[rt][1], 0, 0, 0);
      acc[rt][0] = __builtin_amdgcn_mfma_f32_16x16x32_bf16(ah, bl0, acc[rt][0], 0, 0, 0);
      acc[rt][1] = __builtin_amdgcn_mfma_f32_16x16x32_bf16(ah, bl1, acc[rt][1], 0, 0, 0);
    }
  }

  const int c0 = cb + lr, c1 = cb + 16 + lr;
  const float bb0 = bias[c0], bb1 = bias[c1];
  const float ws0 = wsrc[c0], ws1 = wsrc[c1];
  const float wd0 = wdst[c0], wd1 = wdst[c1];
#pragma unroll
  for (int rt = 0; rt < 4; ++rt) {
#pragma unroll
    for (int j = 0; j < 4; ++j) {
      const int rl = rt * 16 + lg * 4 + j;
      const int row = row0 + rl;
      const float h0 = acc[rt][0][j] + bb0;
      const float h1 = acc[rt][1][j] + bb1;
      float sp = h0 * ws0 + h1 * ws1;
      float dp = h0 * wd0 + h1 * wd1;
#pragma unroll
      for (int m = 1; m <= 8; m <<= 1) {
        sp += __shfl_xor(sp, m, 64);
        dp += __shfl_xor(dp, m, 64);
      }
      if (lr == 0) { atomicAdd(&sred[rl], sp); atomicAdd(&dred[rl], dp); }
      if (row < N) {
        const float sc = dv_isqrt[row];
        Hb[(size_t)row * 128 + c0] = (u16)bf16rne(h0 * sc);
        Hb[(size_t)row * 128 + c1] = (u16)bf16rne(h1 * sc);
      }
    }
  }
  __syncthreads();
  if (tid < 64) {
    const int row = row0 + tid;
    if (row < N) { s_out[row] = sred[tid]; d_out[row] = dred[tid]; }
  }
}

#define ACC8(r, p)                                         \
  a[0] += bflo((r).x) * (p); a[1] += bfhi((r).x) * (p);    \
  a[2] += bflo((r).y) * (p); a[3] += bfhi((r).y) * (p);    \
  a[4] += bflo((r).z) * (p); a[5] += bfhi((r).z) * (p);    \
  a[6] += bflo((r).w) * (p); a[7] += bfhi((r).w) * (p);

// ---------------- M-direction segment sum (P1/P3/P5), 8-deep clamped ----------------
__global__ __launch_bounds__(256) void seg_pass_kernel(
    const u16* __restrict__ src, u16* __restrict__ dst,
    const int* __restrict__ off, const int* __restrict__ lst,
    const float* __restrict__ post_scale, int nseg) {
  const int seg = blockIdx.x * 4 + ((int)threadIdx.x >> 6);
  if (seg >= nseg) return;
  const int lane = (int)threadIdx.x & 63;
  const int q = lane >> 4;
  const int cl = lane & 15;
  const int beg = off[seg], end = off[seg + 1];
  const int last = end - 1;
  float a[8] = {};
  for (int t0 = beg + q; t0 < end; t0 += 32) {
    int jj[8];
    float ww[8];
    jj[0] = lst[t0];
    ww[0] = 1.f;
#pragma unroll
    for (int u = 1; u < 8; ++u) {
      const int t = t0 + 4 * u;
      jj[u] = lst[t <= last ? t : last];
      ww[u] = t <= last ? 1.f : 0.f;
    }
    uint4 rr[8];
#pragma unroll
    for (int u = 0; u < 8; ++u)
      rr[u] = *(const uint4*)(src + (size_t)jj[u] * 128 + cl * 8);
#pragma unroll
    for (int u = 0; u < 8; ++u) {
      const uint4 r = rr[u];
      const float p = ww[u];
      ACC8(r, p)
    }
  }
#pragma unroll
  for (int k = 0; k < 8; ++k) {
    a[k] += __shfl_xor(a[k], 16, 64);
    a[k] += __shfl_xor(a[k], 32, 64);
  }
  if (q != 0) return;
  const float ps = post_scale[seg];
  uint4 pk;
  pk.x = packbf(a[0] * ps, a[1] * ps); pk.y = packbf(a[2] * ps, a[3] * ps);
  pk.z = packbf(a[4] * ps, a[5] * ps); pk.w = packbf(a[6] * ps, a[7] * ps);
  *(uint4*)(dst + (size_t)seg * 128 + cl * 8) = pk;
}

// ---------------- N-direction segment sum (P2/P6), 4-deep clamped ----------------
__global__ __launch_bounds__(256) void segn_pass_kernel(
    const u16* __restrict__ src, void* __restrict__ dst,
    const int* __restrict__ off, const int* __restrict__ lst,
    const float* __restrict__ post_scale, int nseg, int final_mode) {
  const int seg = blockIdx.x * 4 + ((int)threadIdx.x >> 6);
  if (seg >= nseg) return;
  const int lane = (int)threadIdx.x & 63;
  const int q = lane >> 4;
  const int cl = lane & 15;
  const int beg = off[seg], end = off[seg + 1];
  const int last = end - 1;
  float a[8] = {};
  for (int t0 = beg + q; t0 < end; t0 += 16) {
    const int t1 = t0 + 4, t2 = t0 + 8, t3 = t0 + 12;
    const int j0 = lst[t0];
    const int j1 = lst[t1 <= last ? t1 : last];
    const int j2 = lst[t2 <= last ? t2 : last];
    const int j3 = lst[t3 <= last ? t3 : last];
    const float w1 = t1 <= last ? 1.f : 0.f;
    const float w2 = t2 <= last ? 1.f : 0.f;
    const float w3 = t3 <= last ? 1.f : 0.f;
    const uint4 r0 = *(const uint4*)(src + (size_t)j0 * 128 + cl * 8);
    const uint4 r1 = *(const uint4*)(src + (size_t)j1 * 128 + cl * 8);
    const uint4 r2 = *(const uint4*)(src + (size_t)j2 * 128 + cl * 8);
    const uint4 r3 = *(const uint4*)(src + (size_t)j3 * 128 + cl * 8);
    ACC8(r0, 1.0f) ACC8(r1, w1) ACC8(r2, w2) ACC8(r3, w3)
  }
#pragma unroll
  for (int k = 0; k < 8; ++k) {
    a[k] += __shfl_xor(a[k], 16, 64);
    a[k] += __shfl_xor(a[k], 32, 64);
  }
  if (q != 0) return;
  const float ps = post_scale[seg];
#pragma unroll
  for (int k = 0; k < 8; ++k) a[k] *= ps;
  if (final_mode) {
#pragma unroll
    for (int k = 0; k < 8; ++k) a[k] = a[k] > 0.f ? a[k] : __expf(a[k]) - 1.0f;
    float* o = (float*)dst + (size_t)seg * 128 + cl * 8;
    f32x4 v0 = {a[0], a[1], a[2], a[3]};
    f32x4 v1 = {a[4], a[5], a[6], a[7]};
    __builtin_nontemporal_store(v0, (f32x4*)o);
    __builtin_nontemporal_store(v1, (f32x4*)(o + 4));
  } else {
    uint4 pk;
    pk.x = packbf(a[0], a[1]); pk.y = packbf(a[2], a[3]);
    pk.z = packbf(a[4], a[5]); pk.w = packbf(a[6], a[7]);
    *(uint4*)((u16*)dst + (size_t)seg * 128 + cl * 8) = pk;
  }
}

// ---------------- attention e2v (P4), 4-deep clamped ----------------
__global__ __launch_bounds__(256) void attn_pass_kernel(
    const u16* __restrict__ src, u16* __restrict__ dst,
    const int* __restrict__ off, const int2* __restrict__ lst_es, int nseg) {
  const int seg = blockIdx.x * 4 + ((int)threadIdx.x >> 6);
  if (seg >= nseg) return;
  const int lane = (int)threadIdx.x & 63;
  const int q = lane >> 4;
  const int cl = lane & 15;
  const int beg = off[seg], end = off[seg + 1];
  const int last = end - 1;
  float a[8] = {};
  float den = 0.f;
  for (int t0 = beg + q; t0 < end; t0 += 16) {
    const int t1 = t0 + 4, t2 = t0 + 8, t3 = t0 + 12;
    const int2 e0 = lst_es[t0];
    const int2 e1 = lst_es[t1 <= last ? t1 : last];
    const int2 e2 = lst_es[t2 <= last ? t2 : last];
    const int2 e3 = lst_es[t3 <= last ? t3 : last];
    const float s0 = __int_as_float(e0.y);
    const float s1 = t1 <= last ? __int_as_float(e1.y) : 0.f;
    const float s2 = t2 <= last ? __int_as_float(e2.y) : 0.f;
    const float s3 = t3 <= last ? __int_as_float(e3.y) : 0.f;
    const uint4 r0 = *(const uint4*)(src + (size_t)e0.x * 128 + cl * 8);
    const uint4 r1 = *(const uint4*)(src + (size_t)e1.x * 128 + cl * 8);
    const uint4 r2 = *(const uint4*)(src + (size_t)e2.x * 128 + cl * 8);
    const uint4 r3 = *(const uint4*)(src + (size_t)e3.x * 128 + cl * 8);
    ACC8(r0, s0) ACC8(r1, s1) ACC8(r2, s2) ACC8(r3, s3)
    den += s0 + s1 + s2 + s3;
  }
#pragma unroll
  for (int k = 0; k < 8; ++k) {
    a[k] += __shfl_xor(a[k], 16, 64);
    a[k] += __shfl_xor(a[k], 32, 64);
  }
  den += __shfl_xor(den, 16, 64);
  den += __shfl_xor(den, 32, 64);
  const float inv = (end > beg) ? 1.0f / den : 0.0f;
  if (q != 0) return;
  uint4 pk;
  pk.x = packbf(a[0] * inv, a[1] * inv); pk.y = packbf(a[2] * inv, a[3] * inv);
  pk.z = packbf(a[4] * inv, a[5] * inv); pk.w = packbf(a[6] * inv, a[7] * inv);
  *(uint4*)(dst + (size_t)seg * 128 + cl * 8) = pk;
}

extern "C" void kernel_launch(void* const* d_in, const int* in_sizes, int n_in,
                              void* d_out, int out_size, void* d_ws, size_t ws_size,
                              hipStream_t stream) {
  const float* X      = (const float*)d_in[0];
  const int*   pair_v = (const int*)d_in[1];
  const int*   pair_e = (const int*)d_in[2];
  const int*   src_v  = (const int*)d_in[3];
  const float* W      = (const float*)d_in[4];
  const float* bias   = (const float*)d_in[5];
  const float* wsrc   = (const float*)d_in[6];
  const float* wdst   = (const float*)d_in[7];

  const int N = in_sizes[0] / 128;
  const int P = in_sizes[1];
  const int M = M_EDGES;   // fixed by problem definition (pair_e in [0, 50000))
  const int CE = (M + CHUNK - 1) / CHUNK;   // <=256 for partscan
  const int CV = (N + CHUNK - 1) / CHUNK;   // <=256 for partscan

  int SE = 8;
  while ((((M - 1) >> SE) + 1) > NBMAX) ++SE;
  const int NBE = ((M - 1) >> SE) + 1;
  int SV = 9;
  while ((((N - 1) >> SV) + 1) > NBMAX) ++SV;
  const int NBV = ((N - 1) >> SV) + 1;
  const int capgE = P / NBE + P / (NBE * 8) + 256;
  const int capgV = P / NBV + P / (NBV * 8) + 256;

  char* w = (char*)d_ws;
  auto alloc = [&](size_t bytes) -> char* {
    char* p = w;
    w += (bytes + 255) & ~(size_t)255;
    return p;
  };
  int*   cnt_e     = (int*)alloc((size_t)M * 4);
  int*   cnt_v     = (int*)alloc((size_t)N * 4);
  int*   part      = (int*)alloc((size_t)(CE + CV) * 4);
  int*   edge_off  = (int*)alloc((size_t)(M + 1) * 4);
  int*   vtx_off   = (int*)alloc((size_t)(N + 1) * 4);
  float* de_inv    = (float*)alloc((size_t)M * 4);
  float* dv_inv    = (float*)alloc((size_t)N * 4);
  float* dv_isqrt  = (float*)alloc((size_t)N * 4);
  float* svec      = (float*)alloc((size_t)N * 4);
  float* dvec      = (float*)alloc((size_t)N * 4);
  int*   edge_vtx  = (int*)alloc((size_t)P * 4);
  int2*  vtx_es    = (int2*)alloc((size_t)P * 8);
  int*   vtx_edge  = (int*)alloc((size_t)P * 4);
  u16*   bufN      = (u16*)alloc((size_t)N * 128 * 2);  // Hs -> Hs2 -> Xv1 (bf16)
  u16*   bufM      = (u16*)alloc((size_t)M * 128 * 2);  // Xe -> Xe1 -> Xe2 (bf16)
  u32*   binE      = (u32*)alloc((size_t)NBE * capgE * 4);
  uint2* binV      = (uint2*)alloc((size_t)NBV * capgV * 8);
  int*   gcur_e    = (int*)alloc((size_t)NBE * 4);
  int*   gcur_v    = (int*)alloc((size_t)NBV * 4);
  u16*   whi_g     = (u16*)alloc((size_t)128 * 128 * 2);
  u16*   wlo_g     = (u16*)alloc((size_t)128 * 128 * 2);

  prep_w_kernel<<<64, 256, 0, stream>>>(W, whi_g, wlo_g);
  init_gcur_kernel<<<1, 256, 0, stream>>>(gcur_e, gcur_v, NBE, NBV, capgE, capgV);
  bin_edge_kernel<<<(P + TILE_E - 1) / TILE_E, 256, 0, stream>>>(
      pair_e, pair_v, binE, gcur_e, P, SE, NBE);
  bin_vtx_kernel<<<(P + TILE_V - 1) / TILE_V, 256, 0, stream>>>(
      pair_e, pair_v, src_v, binV, gcur_v, P, SV, NBV);
  bucket_hist_kernel<<<NBE + NBV, 256, 0, stream>>>(
      binE, gcur_e, cnt_e, binV, gcur_v, cnt_v, NBE, SE, capgE, SV, capgV, M, N);
  blocksum_kernel<<<CE + CV, 1024, 0, stream>>>(cnt_e, cnt_v, part, CE, M, N);
  partscan_kernel<<<1, 256, 0, stream>>>(part, CE, CV, edge_off, vtx_off, M, N);
  blockscan_kernel<<<CE + CV, 1024, 0, stream>>>(cnt_e, cnt_v, part, edge_off, vtx_off,
                                                 de_inv, dv_inv, dv_isqrt, CE, M, N);
  gemm_mfma_kernel<<<(N + 63) / 64, 256, 0, stream>>>(X, whi_g, wlo_g, bias, wsrc, wdst,
                                                      dv_isqrt, bufN, svec, dvec, N);
  unbin_edge_kernel<<<NBE, 512, 0, stream>>>(binE, gcur_e, edge_off, edge_vtx,
                                             SE, capgE, M);
  unbin_vtx_kernel<<<NBV, 512, 0, stream>>>(binV, gcur_v, vtx_off, vtx_es, vtx_edge,
                                            svec, dvec, SV, capgV, N);

  const int gm = (M + 3) / 4;
  const int gn = (N + 3) / 4;
  // P1: Xe  = de_inv * sum Hs[v]          (dv_isqrt folded into Hs at GEMM)
  seg_pass_kernel<<<gm, 256, 0, stream>>>(bufN, bufM, edge_off, edge_vtx, de_inv, M);
  // P2: Hs2 = dv_isqrt * sum Xe[e]
  segn_pass_kernel<<<gn, 256, 0, stream>>>(bufM, bufN, vtx_off, vtx_edge, dv_isqrt, N, 0);
  // P3: Xe1 = de_inv * sum Hs2[v]
  seg_pass_kernel<<<gm, 256, 0, stream>>>(bufN, bufM, edge_off, edge_vtx, de_inv, M);
  // P4: Xv1 = softmax-weighted sum of Xe1[e]
  attn_pass_kernel<<<gn, 256, 0, stream>>>(bufM, bufN, vtx_off, vtx_es, N);
  // P5: Xe2 = de_inv * sum Xv1[v]
  seg_pass_kernel<<<gm, 256, 0, stream>>>(bufN, bufM, edge_off, edge_vtx, de_inv, M);
  // P6: out = elu(dv_inv * sum Xe2[e])  -> fp32 nontemporal
  segn_pass_kernel<<<gn, 256, 0, stream>>>(bufM, d_out, vtx_off, vtx_edge, dv_inv, N, 1);
}